// Round 5
// baseline (1865.017 us; speedup 1.0000x reference)
//
#include <hip/hip_runtime.h>
#include <math.h>

#define IN_C 64
#define HID_C 128
#define OUT_C 64

// ================= bucketed edge partition =================
// bucket = dst >> 7 (128 nodes per bucket). Cursors are per (bucket, xcd)
// with xcd = blockIdx&7 so each ebuf tail cacheline is written by one XCD
// only (avoids the 16x write amplification k_fill showed in R4).
// ebuf entry: packed = src*128 | (dst & 127)  (src<2^17, fits easily).

__global__ void k_bhist(const int* __restrict__ dst, int* __restrict__ bh, int E) {
  int t = threadIdx.x;
  for (int e = blockIdx.x * 256 + t; e < E; e += gridDim.x * 256) {
    int b = dst[e] >> 7;
    atomicAdd(&bh[b * 8 + (blockIdx.x & 7)], 1);
  }
}

// exclusive scan of 8192 (bucket,xcd) counts -> cursor; bstart[b] = prefix at b*8
__global__ __launch_bounds__(256) void k_bscan(const int* __restrict__ bh,
                                               int* __restrict__ cursor,
                                               int* __restrict__ bstart) {
  __shared__ int s[256];
  int t = threadIdx.x;
  int vals[32];
  int sum = 0;
  int base = t * 32;
#pragma unroll
  for (int j = 0; j < 32; ++j) { vals[j] = bh[base + j]; sum += vals[j]; }
  s[t] = sum;
  __syncthreads();
  for (int off = 1; off < 256; off <<= 1) {
    int a = (t >= off) ? s[t - off] : 0;
    __syncthreads();
    s[t] += a;
    __syncthreads();
  }
  int run = (t == 0) ? 0 : s[t - 1];
#pragma unroll
  for (int j = 0; j < 32; ++j) {
    int idx = base + j;
    cursor[idx] = run;
    if ((idx & 7) == 0) bstart[idx >> 3] = run;
    run += vals[j];
  }
}

__global__ void k_bucket(const int* __restrict__ src, const int* __restrict__ dst,
                         int* __restrict__ cursor, int* __restrict__ ebuf, int E) {
  int t = threadIdx.x;
  int xcd = blockIdx.x & 7;
  for (int e = blockIdx.x * 256 + t; e < E; e += gridDim.x * 256) {
    int d = dst[e];
    int pos = atomicAdd(&cursor[(d >> 7) * 8 + xcd], 1);
    ebuf[pos] = (src[e] << 7) | (d & 127);
  }
}

// ============ fused bucket aggregation (mean), 64-channel table ============
// One block per bucket: 128-node x 64-ch LDS accumulator, ds_add_f32.
// Wave processes edges: coalesced packed-edge load, shfl broadcast, 256B row read.
__global__ __launch_bounds__(256) void k_agg1(const float* __restrict__ x,
                                              const int* __restrict__ ebuf,
                                              const int* __restrict__ bstart,
                                              float* __restrict__ agg, int N, int E) {
  __shared__ float acc[128][64];
  __shared__ int cntl[128];
  int t = threadIdx.x, b = blockIdx.x;
  int lane = t & 63, wv = t >> 6;
  for (int i = t; i < 128 * 64; i += 256) ((float*)acc)[i] = 0.f;
  if (t < 128) cntl[t] = 0;
  __syncthreads();
  int start = bstart[b], end = bstart[b + 1];
  for (int chunk = start + wv * 64; chunk < end; chunk += 256) {
    int p = ebuf[min(chunk + lane, E - 1)];
    int limit = min(64, end - chunk);
    for (int i = 0; i < limit; ++i) {
      int pe = __shfl(p, i);
      int s = pe >> 7, d = pe & 127;
      float v = x[s * 64 + lane];
      atomicAdd(&acc[d][lane], v);
      if (lane == 0) atomicAdd(&cntl[d], 1);
    }
  }
  __syncthreads();
  int nbase = b << 7;
  for (int nl = wv; nl < 128; nl += 4) {
    int node = nbase + nl;
    if (node < N) {
      float inv = 1.0f / fmaxf((float)cntl[nl], 1.0f);
      agg[node * 64 + lane] = acc[nl][lane] * inv;
    }
  }
}

// same, gathering z; epilogue: out = sigmoid(mean_z + r + b2)
__global__ __launch_bounds__(256) void k_agg2(const float* __restrict__ z,
                                              const int* __restrict__ ebuf,
                                              const int* __restrict__ bstart,
                                              const float* __restrict__ r,
                                              const float* __restrict__ b2,
                                              float* __restrict__ out, int N, int E) {
  __shared__ float acc[128][64];
  __shared__ int cntl[128];
  int t = threadIdx.x, b = blockIdx.x;
  int lane = t & 63, wv = t >> 6;
  for (int i = t; i < 128 * 64; i += 256) ((float*)acc)[i] = 0.f;
  if (t < 128) cntl[t] = 0;
  __syncthreads();
  int start = bstart[b], end = bstart[b + 1];
  for (int chunk = start + wv * 64; chunk < end; chunk += 256) {
    int p = ebuf[min(chunk + lane, E - 1)];
    int limit = min(64, end - chunk);
    for (int i = 0; i < limit; ++i) {
      int pe = __shfl(p, i);
      int s = pe >> 7, d = pe & 127;
      float v = z[s * 64 + lane];
      atomicAdd(&acc[d][lane], v);
      if (lane == 0) atomicAdd(&cntl[d], 1);
    }
  }
  __syncthreads();
  float bias = b2[lane];
  int nbase = b << 7;
  for (int nl = wv; nl < 128; nl += 4) {
    int node = nbase + nl;
    if (node < N) {
      float inv = 1.0f / fmaxf((float)cntl[nl], 1.0f);
      float pre = acc[nl][lane] * inv + r[node * 64 + lane] + bias;
      out[node * 64 + lane] = 1.0f / (1.0f + __expf(-pre));
    }
  }
}

// ============ register-blocked fp32 GEMM kernels (unchanged from R4) ============
#define FMA4(ACC, S, W4)                      \
  ACC.x = fmaf((S), (W4).x, ACC.x);           \
  ACC.y = fmaf((S), (W4).y, ACC.y);           \
  ACC.z = fmaf((S), (W4).z, ACC.z);           \
  ACC.w = fmaf((S), (W4).w, ACC.w);

// layer 1: h = relu([agg|x] @ [W1l|W1r]^T + b1)
__global__ __launch_bounds__(512) void k_lin1(
    const float* __restrict__ agg, const float* __restrict__ x,
    const float* __restrict__ W1l, const float* __restrict__ W1r,
    const float* __restrict__ b1, float* __restrict__ h, int N) {
  __shared__ __align__(16) float sW[128 * 132];
  __shared__ __align__(16) float sA[64 * 128];
  int t = threadIdx.x;
  for (int i = t; i < 64 * 128; i += 512) {
    int k = i & 63, c = i >> 6;
    sW[k * 132 + c] = W1l[i];
    sW[(k + 64) * 132 + c] = W1r[i];
  }
  int cg = t & 31, ng = t >> 5;
  int c0 = cg * 4;
  float4 bias = ((const float4*)b1)[cg];
  const float4* agg4 = (const float4*)agg;
  const float4* x4 = (const float4*)x;
  __syncthreads();

  int ntiles = (N + 63) >> 6;
  for (int tile = blockIdx.x; tile < ntiles; tile += gridDim.x) {
    int base = tile << 6;
#pragma unroll
    for (int j = 0; j < 4; ++j) {
      int idx = (t + j * 512) << 2;
      int n = idx >> 7, k = idx & 127;
      int node = base + n;
      float4 v = {0.f, 0.f, 0.f, 0.f};
      if (node < N) v = (k < 64) ? agg4[(node * 64 + k) >> 2]
                                 : x4[(node * 64 + (k - 64)) >> 2];
      *(float4*)(sA + n * 128 + k) = v;
    }
    __syncthreads();
    float4 acc0 = {0, 0, 0, 0}, acc1 = {0, 0, 0, 0}, acc2 = {0, 0, 0, 0}, acc3 = {0, 0, 0, 0};
#pragma unroll 4
    for (int k = 0; k < 128; k += 4) {
      float4 a0 = *(const float4*)(sA + (ng + 0) * 128 + k);
      float4 a1 = *(const float4*)(sA + (ng + 16) * 128 + k);
      float4 a2 = *(const float4*)(sA + (ng + 32) * 128 + k);
      float4 a3 = *(const float4*)(sA + (ng + 48) * 128 + k);
      float4 w0 = *(const float4*)(sW + (k + 0) * 132 + c0);
      float4 w1 = *(const float4*)(sW + (k + 1) * 132 + c0);
      float4 w2 = *(const float4*)(sW + (k + 2) * 132 + c0);
      float4 w3 = *(const float4*)(sW + (k + 3) * 132 + c0);
      FMA4(acc0, a0.x, w0) FMA4(acc1, a1.x, w0) FMA4(acc2, a2.x, w0) FMA4(acc3, a3.x, w0)
      FMA4(acc0, a0.y, w1) FMA4(acc1, a1.y, w1) FMA4(acc2, a2.y, w1) FMA4(acc3, a3.y, w1)
      FMA4(acc0, a0.z, w2) FMA4(acc1, a1.z, w2) FMA4(acc2, a2.z, w2) FMA4(acc3, a3.z, w2)
      FMA4(acc0, a0.w, w3) FMA4(acc1, a1.w, w3) FMA4(acc2, a2.w, w3) FMA4(acc3, a3.w, w3)
    }
    float4 accs[4] = {acc0, acc1, acc2, acc3};
#pragma unroll
    for (int j = 0; j < 4; ++j) {
      int node = base + ng + 16 * j;
      if (node < N) {
        float4 hv;
        hv.x = fmaxf(accs[j].x + bias.x, 0.f);
        hv.y = fmaxf(accs[j].y + bias.y, 0.f);
        hv.z = fmaxf(accs[j].z + bias.z, 0.f);
        hv.w = fmaxf(accs[j].w + bias.w, 0.f);
        *(float4*)(h + node * 128 + c0) = hv;
      }
    }
    __syncthreads();
  }
}

// layer 2: z = h @ W2l^T, r = h @ W2r^T (bias+sigmoid deferred to k_agg2)
__global__ __launch_bounds__(512) void k_lin2(
    const float* __restrict__ h, const float* __restrict__ W2l,
    const float* __restrict__ W2r, float* __restrict__ z,
    float* __restrict__ r, int N) {
  __shared__ __align__(16) float sW[128 * 132];
  __shared__ __align__(16) float sA[64 * 128];
  int t = threadIdx.x;
  for (int i = t; i < 64 * 128; i += 512) {
    int k = i & 127, c = i >> 7;
    sW[k * 132 + c] = W2l[i];
    sW[k * 132 + 64 + c] = W2r[i];
  }
  int cg = t & 31, ng = t >> 5;
  int c0 = cg * 4;
  const float4* h4 = (const float4*)h;
  __syncthreads();

  int ntiles = (N + 63) >> 6;
  for (int tile = blockIdx.x; tile < ntiles; tile += gridDim.x) {
    int base = tile << 6;
#pragma unroll
    for (int j = 0; j < 4; ++j) {
      int idx = (t + j * 512) << 2;
      int n = idx >> 7, k = idx & 127;
      int node = base + n;
      float4 v = {0.f, 0.f, 0.f, 0.f};
      if (node < N) v = h4[(node * 128 + k) >> 2];
      *(float4*)(sA + n * 128 + k) = v;
    }
    __syncthreads();
    float4 acc0 = {0, 0, 0, 0}, acc1 = {0, 0, 0, 0}, acc2 = {0, 0, 0, 0}, acc3 = {0, 0, 0, 0};
#pragma unroll 4
    for (int k = 0; k < 128; k += 4) {
      float4 a0 = *(const float4*)(sA + (ng + 0) * 128 + k);
      float4 a1 = *(const float4*)(sA + (ng + 16) * 128 + k);
      float4 a2 = *(const float4*)(sA + (ng + 32) * 128 + k);
      float4 a3 = *(const float4*)(sA + (ng + 48) * 128 + k);
      float4 w0 = *(const float4*)(sW + (k + 0) * 132 + c0);
      float4 w1 = *(const float4*)(sW + (k + 1) * 132 + c0);
      float4 w2 = *(const float4*)(sW + (k + 2) * 132 + c0);
      float4 w3 = *(const float4*)(sW + (k + 3) * 132 + c0);
      FMA4(acc0, a0.x, w0) FMA4(acc1, a1.x, w0) FMA4(acc2, a2.x, w0) FMA4(acc3, a3.x, w0)
      FMA4(acc0, a0.y, w1) FMA4(acc1, a1.y, w1) FMA4(acc2, a2.y, w1) FMA4(acc3, a3.y, w1)
      FMA4(acc0, a0.z, w2) FMA4(acc1, a1.z, w2) FMA4(acc2, a2.z, w2) FMA4(acc3, a3.z, w2)
      FMA4(acc0, a0.w, w3) FMA4(acc1, a1.w, w3) FMA4(acc2, a2.w, w3) FMA4(acc3, a3.w, w3)
    }
    float4 accs[4] = {acc0, acc1, acc2, acc3};
#pragma unroll
    for (int j = 0; j < 4; ++j) {
      int node = base + ng + 16 * j;
      if (node < N) {
        if (c0 < 64) *(float4*)(z + node * 64 + c0) = accs[j];
        else         *(float4*)(r + node * 64 + (c0 - 64)) = accs[j];
      }
    }
    __syncthreads();
  }
}

extern "C" void kernel_launch(void* const* d_in, const int* in_sizes, int n_in,
                              void* d_out, int out_size, void* d_ws, size_t ws_size,
                              hipStream_t stream) {
  const float* x   = (const float*)d_in[0];
  const int*   ei  = (const int*)d_in[1];
  const float* W1l = (const float*)d_in[2];
  const float* W1r = (const float*)d_in[3];
  const float* b1  = (const float*)d_in[4];
  const float* W2l = (const float*)d_in[5];
  const float* W2r = (const float*)d_in[6];
  const float* b2  = (const float*)d_in[7];
  float* out = (float*)d_out;

  int N = in_sizes[0] / IN_C;
  int E = in_sizes[1] / 2;
  const int* src = ei;
  const int* dst = ei + E;

  // ws layout: [bh 8192][cursor 8192][bstart 1024][ebuf E]
  //            [agg N*64 f][z N*64 f][r N*64 f][h N*128 f]
  char* ws = (char*)d_ws;
  size_t off = 0;
  auto alignup = [](size_t v) { return (v + 511) & ~(size_t)511; };
  int* bh = (int*)(ws + off);         off = alignup(off + 8192 * 4);
  int* cursor = (int*)(ws + off);     off = alignup(off + 8192 * 4);
  int* bstart = (int*)(ws + off);     off = alignup(off + 1024 * 4);
  int* ebuf = (int*)(ws + off);       off = alignup(off + (size_t)E * 4);
  float* aggbuf = (float*)(ws + off); off = alignup(off + (size_t)N * 64 * 4);
  float* zbuf = (float*)(ws + off);   off = alignup(off + (size_t)N * 64 * 4);
  float* rbuf = (float*)(ws + off);   off = alignup(off + (size_t)N * 64 * 4);
  float* hbuf = (float*)(ws + off);

  int NBUCK = (N + 127) >> 7;

  // bucketed edge partition
  hipMemsetAsync(bh, 0, 8192 * 4, stream);
  k_bhist<<<2048, 256, 0, stream>>>(dst, bh, E);
  k_bscan<<<1, 256, 0, stream>>>(bh, cursor, bstart);
  k_bucket<<<2048, 256, 0, stream>>>(src, dst, cursor, ebuf, E);

  // layer 1
  k_agg1<<<NBUCK, 256, 0, stream>>>(x, ebuf, bstart, aggbuf, N, E);
  k_lin1<<<256, 512, 0, stream>>>(aggbuf, x, W1l, W1r, b1, hbuf, N);
  // layer 2
  k_lin2<<<256, 512, 0, stream>>>(hbuf, W2l, W2r, zbuf, rbuf, N);
  k_agg2<<<NBUCK, 256, 0, stream>>>(zbuf, ebuf, bstart, rbuf, b2, out, N, E);
}

// Round 6
// 521.906 us; speedup vs baseline: 3.5735x; 3.5735x over previous
//
#include <hip/hip_runtime.h>
#include <math.h>

#define IN_C 64
#define HID_C 128
#define OUT_C 64

// ================= bucketed edge partition (R5, proven cheap) =================
// bucket = dst >> 7 (128 nodes). Cursors per (bucket, blockIdx&7) so ebuf tail
// lines are written from one XCD-ish stream each (kills R4 k_fill's 16x write amp).
// ebuf entry: packed = (src << 7) | (dst & 127).

__global__ void k_bhist(const int* __restrict__ dst, int* __restrict__ bh, int E) {
  int t = threadIdx.x;
  for (int e = blockIdx.x * 256 + t; e < E; e += gridDim.x * 256) {
    int b = dst[e] >> 7;
    atomicAdd(&bh[b * 8 + (blockIdx.x & 7)], 1);
  }
}

__global__ __launch_bounds__(256) void k_bscan(const int* __restrict__ bh,
                                               int* __restrict__ cursor,
                                               int* __restrict__ bstart) {
  __shared__ int s[256];
  int t = threadIdx.x;
  int vals[32];
  int sum = 0;
  int base = t * 32;
#pragma unroll
  for (int j = 0; j < 32; ++j) { vals[j] = bh[base + j]; sum += vals[j]; }
  s[t] = sum;
  __syncthreads();
  for (int off = 1; off < 256; off <<= 1) {
    int a = (t >= off) ? s[t - off] : 0;
    __syncthreads();
    s[t] += a;
    __syncthreads();
  }
  int run = (t == 0) ? 0 : s[t - 1];
#pragma unroll
  for (int j = 0; j < 32; ++j) {
    int idx = base + j;
    cursor[idx] = run;
    if ((idx & 7) == 0) bstart[idx >> 3] = run;
    run += vals[j];
  }
}

__global__ void k_bucket(const int* __restrict__ src, const int* __restrict__ dst,
                         int* __restrict__ cursor, int* __restrict__ ebuf, int E) {
  int t = threadIdx.x;
  int xcd = blockIdx.x & 7;
  for (int e = blockIdx.x * 256 + t; e < E; e += gridDim.x * 256) {
    int d = dst[e];
    int pos = atomicAdd(&cursor[(d >> 7) * 8 + xcd], 1);
    ebuf[pos] = (src[e] << 7) | (d & 127);
  }
}

// ============ per-bucket local CSR: block = bucket ============
// LDS histogram over 128 local nodes + scan, then scatter src into the bucket's
// contiguous csr segment (~8KB: lines touched by this block only -> no write amp).
// Also emits row_start[] and cnt[] per node.
__global__ __launch_bounds__(256) void k_localcsr(const int* __restrict__ ebuf,
                                                  const int* __restrict__ bstart,
                                                  int* __restrict__ csr,
                                                  int* __restrict__ row_start,
                                                  int* __restrict__ cnt, int N) {
  __shared__ int lcnt[128], loff[128], lcur[128];
  int t = threadIdx.x, b = blockIdx.x;
  int start = bstart[b], end = bstart[b + 1];
  if (t < 128) lcnt[t] = 0;
  __syncthreads();
  for (int i = start + t; i < end; i += 256) atomicAdd(&lcnt[ebuf[i] & 127], 1);
  __syncthreads();
  if (t == 0) {
    int run = 0;
    for (int l = 0; l < 128; ++l) { loff[l] = run; run += lcnt[l]; }
  }
  __syncthreads();
  if (t < 128) {
    lcur[t] = loff[t];
    int node = (b << 7) + t;
    if (node < N) { row_start[node] = start + loff[t]; cnt[node] = lcnt[t]; }
  }
  __syncthreads();
  for (int i = start + t; i < end; i += 256) {
    int pe = ebuf[i];
    int pos = atomicAdd(&lcur[pe & 127], 1);
    csr[start + pos] = pe >> 7;
  }
}

// ============ gather 1 (R4): agg1[i] = mean_{j} x[j], wave/node ============
__global__ __launch_bounds__(256) void k_gather1(const float* __restrict__ x,
                                                 const int* __restrict__ csr,
                                                 const int* __restrict__ row_start,
                                                 const int* __restrict__ cnt,
                                                 float* __restrict__ agg, int N) {
  int wid = (blockIdx.x * blockDim.x + threadIdx.x) >> 6;
  int lane = threadIdx.x & 63;
  if (wid >= N) return;
  int start = row_start[wid];
  int c = cnt[wid];
  int j = start, end = start + c;
  float v = 0.f;
  for (; j + 3 < end; j += 4) {
    int s0 = csr[j], s1 = csr[j + 1], s2 = csr[j + 2], s3 = csr[j + 3];
    float a0 = x[s0 * IN_C + lane];
    float a1 = x[s1 * IN_C + lane];
    float a2 = x[s2 * IN_C + lane];
    float a3 = x[s3 * IN_C + lane];
    v += a0 + a1 + a2 + a3;
  }
  for (; j < end; ++j) v += x[csr[j] * IN_C + lane];
  float inv = 1.0f / fmaxf((float)c, 1.0f);
  agg[wid * IN_C + lane] = v * inv;
}

// ============ register-blocked fp32 GEMM kernels (R4) ============
#define FMA4(ACC, S, W4)                      \
  ACC.x = fmaf((S), (W4).x, ACC.x);           \
  ACC.y = fmaf((S), (W4).y, ACC.y);           \
  ACC.z = fmaf((S), (W4).z, ACC.z);           \
  ACC.w = fmaf((S), (W4).w, ACC.w);

// layer 1: h = relu([agg|x] @ [W1l|W1r]^T + b1)
__global__ __launch_bounds__(512) void k_lin1(
    const float* __restrict__ agg, const float* __restrict__ x,
    const float* __restrict__ W1l, const float* __restrict__ W1r,
    const float* __restrict__ b1, float* __restrict__ h, int N) {
  __shared__ __align__(16) float sW[128 * 132];
  __shared__ __align__(16) float sA[64 * 128];
  int t = threadIdx.x;
  for (int i = t; i < 64 * 128; i += 512) {
    int k = i & 63, c = i >> 6;
    sW[k * 132 + c] = W1l[i];
    sW[(k + 64) * 132 + c] = W1r[i];
  }
  int cg = t & 31, ng = t >> 5;
  int c0 = cg * 4;
  float4 bias = ((const float4*)b1)[cg];
  const float4* agg4 = (const float4*)agg;
  const float4* x4 = (const float4*)x;
  __syncthreads();

  int ntiles = (N + 63) >> 6;
  for (int tile = blockIdx.x; tile < ntiles; tile += gridDim.x) {
    int base = tile << 6;
#pragma unroll
    for (int j = 0; j < 4; ++j) {
      int idx = (t + j * 512) << 2;
      int n = idx >> 7, k = idx & 127;
      int node = base + n;
      float4 v = {0.f, 0.f, 0.f, 0.f};
      if (node < N) v = (k < 64) ? agg4[(node * 64 + k) >> 2]
                                 : x4[(node * 64 + (k - 64)) >> 2];
      *(float4*)(sA + n * 128 + k) = v;
    }
    __syncthreads();
    float4 acc0 = {0, 0, 0, 0}, acc1 = {0, 0, 0, 0}, acc2 = {0, 0, 0, 0}, acc3 = {0, 0, 0, 0};
#pragma unroll 4
    for (int k = 0; k < 128; k += 4) {
      float4 a0 = *(const float4*)(sA + (ng + 0) * 128 + k);
      float4 a1 = *(const float4*)(sA + (ng + 16) * 128 + k);
      float4 a2 = *(const float4*)(sA + (ng + 32) * 128 + k);
      float4 a3 = *(const float4*)(sA + (ng + 48) * 128 + k);
      float4 w0 = *(const float4*)(sW + (k + 0) * 132 + c0);
      float4 w1 = *(const float4*)(sW + (k + 1) * 132 + c0);
      float4 w2 = *(const float4*)(sW + (k + 2) * 132 + c0);
      float4 w3 = *(const float4*)(sW + (k + 3) * 132 + c0);
      FMA4(acc0, a0.x, w0) FMA4(acc1, a1.x, w0) FMA4(acc2, a2.x, w0) FMA4(acc3, a3.x, w0)
      FMA4(acc0, a0.y, w1) FMA4(acc1, a1.y, w1) FMA4(acc2, a2.y, w1) FMA4(acc3, a3.y, w1)
      FMA4(acc0, a0.z, w2) FMA4(acc1, a1.z, w2) FMA4(acc2, a2.z, w2) FMA4(acc3, a3.z, w2)
      FMA4(acc0, a0.w, w3) FMA4(acc1, a1.w, w3) FMA4(acc2, a2.w, w3) FMA4(acc3, a3.w, w3)
    }
    float4 accs[4] = {acc0, acc1, acc2, acc3};
#pragma unroll
    for (int j = 0; j < 4; ++j) {
      int node = base + ng + 16 * j;
      if (node < N) {
        float4 hv;
        hv.x = fmaxf(accs[j].x + bias.x, 0.f);
        hv.y = fmaxf(accs[j].y + bias.y, 0.f);
        hv.z = fmaxf(accs[j].z + bias.z, 0.f);
        hv.w = fmaxf(accs[j].w + bias.w, 0.f);
        *(float4*)(h + node * 128 + c0) = hv;
      }
    }
    __syncthreads();
  }
}

// layer 2: z = h @ W2l^T, r = h @ W2r^T (bias+sigmoid deferred to gather2b)
__global__ __launch_bounds__(512) void k_lin2(
    const float* __restrict__ h, const float* __restrict__ W2l,
    const float* __restrict__ W2r, float* __restrict__ z,
    float* __restrict__ r, int N) {
  __shared__ __align__(16) float sW[128 * 132];
  __shared__ __align__(16) float sA[64 * 128];
  int t = threadIdx.x;
  for (int i = t; i < 64 * 128; i += 512) {
    int k = i & 127, c = i >> 7;
    sW[k * 132 + c] = W2l[i];
    sW[k * 132 + 64 + c] = W2r[i];
  }
  int cg = t & 31, ng = t >> 5;
  int c0 = cg * 4;
  const float4* h4 = (const float4*)h;
  __syncthreads();

  int ntiles = (N + 63) >> 6;
  for (int tile = blockIdx.x; tile < ntiles; tile += gridDim.x) {
    int base = tile << 6;
#pragma unroll
    for (int j = 0; j < 4; ++j) {
      int idx = (t + j * 512) << 2;
      int n = idx >> 7, k = idx & 127;
      int node = base + n;
      float4 v = {0.f, 0.f, 0.f, 0.f};
      if (node < N) v = h4[(node * 128 + k) >> 2];
      *(float4*)(sA + n * 128 + k) = v;
    }
    __syncthreads();
    float4 acc0 = {0, 0, 0, 0}, acc1 = {0, 0, 0, 0}, acc2 = {0, 0, 0, 0}, acc3 = {0, 0, 0, 0};
#pragma unroll 4
    for (int k = 0; k < 128; k += 4) {
      float4 a0 = *(const float4*)(sA + (ng + 0) * 128 + k);
      float4 a1 = *(const float4*)(sA + (ng + 16) * 128 + k);
      float4 a2 = *(const float4*)(sA + (ng + 32) * 128 + k);
      float4 a3 = *(const float4*)(sA + (ng + 48) * 128 + k);
      float4 w0 = *(const float4*)(sW + (k + 0) * 132 + c0);
      float4 w1 = *(const float4*)(sW + (k + 1) * 132 + c0);
      float4 w2 = *(const float4*)(sW + (k + 2) * 132 + c0);
      float4 w3 = *(const float4*)(sW + (k + 3) * 132 + c0);
      FMA4(acc0, a0.x, w0) FMA4(acc1, a1.x, w0) FMA4(acc2, a2.x, w0) FMA4(acc3, a3.x, w0)
      FMA4(acc0, a0.y, w1) FMA4(acc1, a1.y, w1) FMA4(acc2, a2.y, w1) FMA4(acc3, a3.y, w1)
      FMA4(acc0, a0.z, w2) FMA4(acc1, a1.z, w2) FMA4(acc2, a2.z, w2) FMA4(acc3, a3.z, w2)
      FMA4(acc0, a0.w, w3) FMA4(acc1, a1.w, w3) FMA4(acc2, a2.w, w3) FMA4(acc3, a3.w, w3)
    }
    float4 accs[4] = {acc0, acc1, acc2, acc3};
#pragma unroll
    for (int j = 0; j < 4; ++j) {
      int node = base + ng + 16 * j;
      if (node < N) {
        if (c0 < 64) *(float4*)(z + node * 64 + c0) = accs[j];
        else         *(float4*)(r + node * 64 + (c0 - 64)) = accs[j];
      }
    }
    __syncthreads();
  }
}

// ==== gather 2 + epilogue (R4): out = sigmoid(mean_z + r + b2) ========
__global__ __launch_bounds__(256) void k_gather2b(const float* __restrict__ z,
                                                  const float* __restrict__ r,
                                                  const float* __restrict__ b2,
                                                  const int* __restrict__ csr,
                                                  const int* __restrict__ row_start,
                                                  const int* __restrict__ cnt,
                                                  float* __restrict__ out, int N) {
  int wid = (blockIdx.x * blockDim.x + threadIdx.x) >> 6;
  int lane = threadIdx.x & 63;
  if (wid >= N) return;
  int start = row_start[wid];
  int c = cnt[wid];
  int j = start, end = start + c;
  float v = 0.f;
  for (; j + 3 < end; j += 4) {
    int s0 = csr[j], s1 = csr[j + 1], s2 = csr[j + 2], s3 = csr[j + 3];
    float a0 = z[s0 * 64 + lane];
    float a1 = z[s1 * 64 + lane];
    float a2 = z[s2 * 64 + lane];
    float a3 = z[s3 * 64 + lane];
    v += a0 + a1 + a2 + a3;
  }
  for (; j < end; ++j) v += z[csr[j] * 64 + lane];
  float inv = 1.0f / fmaxf((float)c, 1.0f);
  float pre = v * inv + r[wid * 64 + lane] + b2[lane];
  out[wid * 64 + lane] = 1.0f / (1.0f + __expf(-pre));
}

extern "C" void kernel_launch(void* const* d_in, const int* in_sizes, int n_in,
                              void* d_out, int out_size, void* d_ws, size_t ws_size,
                              hipStream_t stream) {
  const float* x   = (const float*)d_in[0];
  const int*   ei  = (const int*)d_in[1];
  const float* W1l = (const float*)d_in[2];
  const float* W1r = (const float*)d_in[3];
  const float* b1  = (const float*)d_in[4];
  const float* W2l = (const float*)d_in[5];
  const float* W2r = (const float*)d_in[6];
  const float* b2  = (const float*)d_in[7];
  float* out = (float*)d_out;

  int N = in_sizes[0] / IN_C;
  int E = in_sizes[1] / 2;
  const int* src = ei;
  const int* dst = ei + E;

  // ws layout: [bh 8192][cursor 8192][bstart 1024][csr E][row_start N][cnt N]
  //            [agg N*64 f  (ebuf E aliases its start)][z N*64][r N*64][h N*128]
  char* ws = (char*)d_ws;
  size_t off = 0;
  auto alignup = [](size_t v) { return (v + 511) & ~(size_t)511; };
  int* bh = (int*)(ws + off);         off = alignup(off + 8192 * 4);
  int* cursor = (int*)(ws + off);     off = alignup(off + 8192 * 4);
  int* bstart = (int*)(ws + off);     off = alignup(off + 1024 * 4);
  int* csr = (int*)(ws + off);        off = alignup(off + (size_t)E * 4);
  int* row_start = (int*)(ws + off);  off = alignup(off + (size_t)N * 4);
  int* cnt = (int*)(ws + off);        off = alignup(off + (size_t)N * 4);
  float* aggbuf = (float*)(ws + off); off = alignup(off + (size_t)N * 64 * 4);
  float* zbuf = (float*)(ws + off);   off = alignup(off + (size_t)N * 64 * 4);
  float* rbuf = (float*)(ws + off);   off = alignup(off + (size_t)N * 64 * 4);
  float* hbuf = (float*)(ws + off);
  int* ebuf = (int*)aggbuf;  // dead before k_gather1 writes aggbuf

  int NBUCK = (N + 127) >> 7;

  // bucketed edge partition -> per-bucket local CSR
  hipMemsetAsync(bh, 0, 8192 * 4, stream);
  k_bhist<<<2048, 256, 0, stream>>>(dst, bh, E);
  k_bscan<<<1, 256, 0, stream>>>(bh, cursor, bstart);
  k_bucket<<<2048, 256, 0, stream>>>(src, dst, cursor, ebuf, E);
  k_localcsr<<<NBUCK, 256, 0, stream>>>(ebuf, bstart, csr, row_start, cnt, N);

  // layer 1
  k_gather1<<<(N + 3) / 4, 256, 0, stream>>>(x, csr, row_start, cnt, aggbuf, N);
  k_lin1<<<256, 512, 0, stream>>>(aggbuf, x, W1l, W1r, b1, hbuf, N);
  // layer 2
  k_lin2<<<256, 512, 0, stream>>>(hbuf, W2l, W2r, zbuf, rbuf, N);
  k_gather2b<<<(N + 3) / 4, 256, 0, stream>>>(zbuf, rbuf, b2, csr, row_start, cnt,
                                              out, N);
}

// Round 7
// 438.543 us; speedup vs baseline: 4.2528x; 1.1901x over previous
//
#include <hip/hip_runtime.h>
#include <math.h>

#define IN_C 64
#define HID_C 128
#define OUT_C 64
// buckets of 256 nodes: bucket = dst >> 8; packed edge = (src<<8)|(dst&255)
// sentinel -1 is unreachable (src < 2^17, packed < 2^25)

// ======== bhist: LDS-local 512-bin histogram, one merge add per bin ========
__global__ __launch_bounds__(256) void k_bhistL(const int* __restrict__ dst,
                                                int* __restrict__ bh, int E) {
  __shared__ int h[512];
  int t = threadIdx.x;
  h[t] = 0; h[t + 256] = 0;
  __syncthreads();
  for (int e = blockIdx.x * 256 + t; e < E; e += gridDim.x * 256)
    atomicAdd(&h[dst[e] >> 8], 1);
  __syncthreads();
  if (h[t]) atomicAdd(&bh[t], h[t]);
  if (h[t + 256]) atomicAdd(&bh[t + 256], h[t + 256]);
}

// ======== scan: chunked (slack) region starts + dense csr starts ========
// region = 16*min(cnt, cnt/16 + 256): worst-case chunks = cnt/16 + one
// residual chunk per writer block (grid=256) — deterministically safe.
__global__ __launch_bounds__(512) void k_bscan(const int* __restrict__ bh,
                                               int* __restrict__ bstart,
                                               int* __restrict__ rstart,
                                               int* __restrict__ gcur) {
  __shared__ int s1[512], s2[512];
  int t = threadIdx.x;
  int cnt = bh[t];
  int region = 16 * min(cnt, (cnt >> 4) + 256);
  s1[t] = region; s2[t] = cnt;
  __syncthreads();
  for (int off = 1; off < 512; off <<= 1) {
    int a1 = (t >= off) ? s1[t - off] : 0;
    int a2 = (t >= off) ? s2[t - off] : 0;
    __syncthreads();
    s1[t] += a1; s2[t] += a2;
    __syncthreads();
  }
  int ex1 = s1[t] - region;
  int ex2 = s2[t] - cnt;
  bstart[t] = ex1; gcur[t] = ex1; rstart[t] = ex2;
}

// ======== multisplit: LDS-buffered, 64B line-aligned single-owner flushes ====
__global__ __launch_bounds__(256) void k_msplit(const int* __restrict__ src,
                                                const int* __restrict__ dst,
                                                int* __restrict__ gcur,
                                                int* __restrict__ ebuf, int E) {
  __shared__ int bcnt[512];
  __shared__ __align__(16) int bins[512][32];
  int t = threadIdx.x;
  bcnt[t] = 0; bcnt[t + 256] = 0;
  int per = (E + gridDim.x - 1) / gridDim.x;
  int e0 = blockIdx.x * per, e1 = min(E, e0 + per);
  int e = e0 + t;
  int pb[2], pv[2]; int pc = 0;
  __syncthreads();
  for (;;) {
    // phase A: fetch (if room) + try place pending edges
    if (pc < 2 && e < e1) {
      int d = dst[e], s = src[e];
      pb[pc] = d >> 8; pv[pc] = (s << 8) | (d & 255);
      pc++; e += 256;
    }
    for (int q = pc - 1; q >= 0; --q) {
      int pos = atomicAdd(&bcnt[pb[q]], 1);
      if (pos < 32) {
        bins[pb[q]][pos] = pv[q];
        pc--; pb[q] = pb[pc]; pv[q] = pv[pc];
      }
    }
    int pending = __syncthreads_count(pc > 0 || e < e1);
    // phase B: drain full 16-entry chunks (owner thread per bin, 2 bins/thread)
    for (int b = t; b < 512; b += 256) {
      int real = min(bcnt[b], 32);
      while (real >= 16) {
        int base = atomicAdd(&gcur[b], 16);
        int4* gout = (int4*)(ebuf + base);
        const int4* lb = (const int4*)(&bins[b][0]);
        gout[0] = lb[0]; gout[1] = lb[1]; gout[2] = lb[2]; gout[3] = lb[3];
        real -= 16;
        for (int k = 0; k < real; ++k) bins[b][k] = bins[b][k + 16];
      }
      bcnt[b] = real;
    }
    __syncthreads();
    if (!pending) break;
  }
  // residual: full-line chunk, sentinel-padded (line still single-owner)
  for (int b = t; b < 512; b += 256) {
    int realv = bcnt[b];
    if (realv > 0) {
      int base = atomicAdd(&gcur[b], 16);
#pragma unroll
      for (int k = 0; k < 16; ++k) ebuf[base + k] = (k < realv) ? bins[b][k] : -1;
    }
  }
}

// ======== per-bucket local CSR (256 nodes/bucket, skips sentinels) ========
__global__ __launch_bounds__(256) void k_localcsr(const int* __restrict__ ebuf,
                                                  const int* __restrict__ bstart,
                                                  const int* __restrict__ gcur,
                                                  const int* __restrict__ rstart,
                                                  int* __restrict__ csr,
                                                  int* __restrict__ row_start,
                                                  int* __restrict__ cnt, int N) {
  __shared__ int lcnt[256], loff[256], lcur[256];
  int t = threadIdx.x, b = blockIdx.x;
  int start = bstart[b], endp = gcur[b], rs = rstart[b];
  lcnt[t] = 0;
  __syncthreads();
  for (int i = start + t; i < endp; i += 256) {
    int pe = ebuf[i];
    if (pe != -1) atomicAdd(&lcnt[pe & 255], 1);
  }
  __syncthreads();
  int v = lcnt[t];
  loff[t] = v;
  __syncthreads();
  for (int off = 1; off < 256; off <<= 1) {
    int a = (t >= off) ? loff[t - off] : 0;
    __syncthreads();
    loff[t] += a;
    __syncthreads();
  }
  int ex = loff[t] - v;
  lcur[t] = ex;
  int node = (b << 8) + t;
  if (node < N) { row_start[node] = rs + ex; cnt[node] = v; }
  __syncthreads();
  for (int i = start + t; i < endp; i += 256) {
    int pe = ebuf[i];
    if (pe != -1) {
      int pos = atomicAdd(&lcur[pe & 255], 1);
      csr[rs + pos] = pe >> 8;
    }
  }
}

// ======== gather 1: wave/node, lane=(edge-group, chan-quad), float4 ========
__global__ __launch_bounds__(256) void k_gather1(const float* __restrict__ x,
                                                 const int* __restrict__ csr,
                                                 const int* __restrict__ row_start,
                                                 const int* __restrict__ cnt,
                                                 float* __restrict__ agg, int N) {
  int wid = (blockIdx.x * blockDim.x + threadIdx.x) >> 6;
  int lane = threadIdx.x & 63;
  if (wid >= N) return;
  int egrp = lane >> 4, cq = lane & 15;
  const float4* x4 = (const float4*)x;
  int start = row_start[wid], c = cnt[wid], end = start + c;
  float4 acc = {0.f, 0.f, 0.f, 0.f};
  for (int j = start; j < end; j += 8) {
    int ea = j + egrp, eb = j + 4 + egrp;
    if (ea < end) {
      float4 va = x4[csr[ea] * 16 + cq];
      acc.x += va.x; acc.y += va.y; acc.z += va.z; acc.w += va.w;
    }
    if (eb < end) {
      float4 vb = x4[csr[eb] * 16 + cq];
      acc.x += vb.x; acc.y += vb.y; acc.z += vb.z; acc.w += vb.w;
    }
  }
  acc.x += __shfl_xor(acc.x, 32); acc.y += __shfl_xor(acc.y, 32);
  acc.z += __shfl_xor(acc.z, 32); acc.w += __shfl_xor(acc.w, 32);
  acc.x += __shfl_xor(acc.x, 16); acc.y += __shfl_xor(acc.y, 16);
  acc.z += __shfl_xor(acc.z, 16); acc.w += __shfl_xor(acc.w, 16);
  if (lane < 16) {
    float inv = 1.0f / fmaxf((float)c, 1.0f);
    float4 o = {acc.x * inv, acc.y * inv, acc.z * inv, acc.w * inv};
    ((float4*)agg)[wid * 16 + cq] = o;
  }
}

// ======== register-blocked fp32 GEMM kernels (R4, proven) ========
#define FMA4(ACC, S, W4)                      \
  ACC.x = fmaf((S), (W4).x, ACC.x);           \
  ACC.y = fmaf((S), (W4).y, ACC.y);           \
  ACC.z = fmaf((S), (W4).z, ACC.z);           \
  ACC.w = fmaf((S), (W4).w, ACC.w);

__global__ __launch_bounds__(512) void k_lin1(
    const float* __restrict__ agg, const float* __restrict__ x,
    const float* __restrict__ W1l, const float* __restrict__ W1r,
    const float* __restrict__ b1, float* __restrict__ h, int N) {
  __shared__ __align__(16) float sW[128 * 132];
  __shared__ __align__(16) float sA[64 * 128];
  int t = threadIdx.x;
  for (int i = t; i < 64 * 128; i += 512) {
    int k = i & 63, c = i >> 6;
    sW[k * 132 + c] = W1l[i];
    sW[(k + 64) * 132 + c] = W1r[i];
  }
  int cg = t & 31, ng = t >> 5;
  int c0 = cg * 4;
  float4 bias = ((const float4*)b1)[cg];
  const float4* agg4 = (const float4*)agg;
  const float4* x4 = (const float4*)x;
  __syncthreads();

  int ntiles = (N + 63) >> 6;
  for (int tile = blockIdx.x; tile < ntiles; tile += gridDim.x) {
    int base = tile << 6;
#pragma unroll
    for (int j = 0; j < 4; ++j) {
      int idx = (t + j * 512) << 2;
      int n = idx >> 7, k = idx & 127;
      int node = base + n;
      float4 v = {0.f, 0.f, 0.f, 0.f};
      if (node < N) v = (k < 64) ? agg4[(node * 64 + k) >> 2]
                                 : x4[(node * 64 + (k - 64)) >> 2];
      *(float4*)(sA + n * 128 + k) = v;
    }
    __syncthreads();
    float4 acc0 = {0, 0, 0, 0}, acc1 = {0, 0, 0, 0}, acc2 = {0, 0, 0, 0}, acc3 = {0, 0, 0, 0};
#pragma unroll 4
    for (int k = 0; k < 128; k += 4) {
      float4 a0 = *(const float4*)(sA + (ng + 0) * 128 + k);
      float4 a1 = *(const float4*)(sA + (ng + 16) * 128 + k);
      float4 a2 = *(const float4*)(sA + (ng + 32) * 128 + k);
      float4 a3 = *(const float4*)(sA + (ng + 48) * 128 + k);
      float4 w0 = *(const float4*)(sW + (k + 0) * 132 + c0);
      float4 w1 = *(const float4*)(sW + (k + 1) * 132 + c0);
      float4 w2 = *(const float4*)(sW + (k + 2) * 132 + c0);
      float4 w3 = *(const float4*)(sW + (k + 3) * 132 + c0);
      FMA4(acc0, a0.x, w0) FMA4(acc1, a1.x, w0) FMA4(acc2, a2.x, w0) FMA4(acc3, a3.x, w0)
      FMA4(acc0, a0.y, w1) FMA4(acc1, a1.y, w1) FMA4(acc2, a2.y, w1) FMA4(acc3, a3.y, w1)
      FMA4(acc0, a0.z, w2) FMA4(acc1, a1.z, w2) FMA4(acc2, a2.z, w2) FMA4(acc3, a3.z, w2)
      FMA4(acc0, a0.w, w3) FMA4(acc1, a1.w, w3) FMA4(acc2, a2.w, w3) FMA4(acc3, a3.w, w3)
    }
    float4 accs[4] = {acc0, acc1, acc2, acc3};
#pragma unroll
    for (int j = 0; j < 4; ++j) {
      int node = base + ng + 16 * j;
      if (node < N) {
        float4 hv;
        hv.x = fmaxf(accs[j].x + bias.x, 0.f);
        hv.y = fmaxf(accs[j].y + bias.y, 0.f);
        hv.z = fmaxf(accs[j].z + bias.z, 0.f);
        hv.w = fmaxf(accs[j].w + bias.w, 0.f);
        *(float4*)(h + node * 128 + c0) = hv;
      }
    }
    __syncthreads();
  }
}

__global__ __launch_bounds__(512) void k_lin2(
    const float* __restrict__ h, const float* __restrict__ W2l,
    const float* __restrict__ W2r, float* __restrict__ z,
    float* __restrict__ r, int N) {
  __shared__ __align__(16) float sW[128 * 132];
  __shared__ __align__(16) float sA[64 * 128];
  int t = threadIdx.x;
  for (int i = t; i < 64 * 128; i += 512) {
    int k = i & 127, c = i >> 7;
    sW[k * 132 + c] = W2l[i];
    sW[k * 132 + 64 + c] = W2r[i];
  }
  int cg = t & 31, ng = t >> 5;
  int c0 = cg * 4;
  const float4* h4 = (const float4*)h;
  __syncthreads();

  int ntiles = (N + 63) >> 6;
  for (int tile = blockIdx.x; tile < ntiles; tile += gridDim.x) {
    int base = tile << 6;
#pragma unroll
    for (int j = 0; j < 4; ++j) {
      int idx = (t + j * 512) << 2;
      int n = idx >> 7, k = idx & 127;
      int node = base + n;
      float4 v = {0.f, 0.f, 0.f, 0.f};
      if (node < N) v = h4[(node * 128 + k) >> 2];
      *(float4*)(sA + n * 128 + k) = v;
    }
    __syncthreads();
    float4 acc0 = {0, 0, 0, 0}, acc1 = {0, 0, 0, 0}, acc2 = {0, 0, 0, 0}, acc3 = {0, 0, 0, 0};
#pragma unroll 4
    for (int k = 0; k < 128; k += 4) {
      float4 a0 = *(const float4*)(sA + (ng + 0) * 128 + k);
      float4 a1 = *(const float4*)(sA + (ng + 16) * 128 + k);
      float4 a2 = *(const float4*)(sA + (ng + 32) * 128 + k);
      float4 a3 = *(const float4*)(sA + (ng + 48) * 128 + k);
      float4 w0 = *(const float4*)(sW + (k + 0) * 132 + c0);
      float4 w1 = *(const float4*)(sW + (k + 1) * 132 + c0);
      float4 w2 = *(const float4*)(sW + (k + 2) * 132 + c0);
      float4 w3 = *(const float4*)(sW + (k + 3) * 132 + c0);
      FMA4(acc0, a0.x, w0) FMA4(acc1, a1.x, w0) FMA4(acc2, a2.x, w0) FMA4(acc3, a3.x, w0)
      FMA4(acc0, a0.y, w1) FMA4(acc1, a1.y, w1) FMA4(acc2, a2.y, w1) FMA4(acc3, a3.y, w1)
      FMA4(acc0, a0.z, w2) FMA4(acc1, a1.z, w2) FMA4(acc2, a2.z, w2) FMA4(acc3, a3.z, w2)
      FMA4(acc0, a0.w, w3) FMA4(acc1, a1.w, w3) FMA4(acc2, a2.w, w3) FMA4(acc3, a3.w, w3)
    }
    float4 accs[4] = {acc0, acc1, acc2, acc3};
#pragma unroll
    for (int j = 0; j < 4; ++j) {
      int node = base + ng + 16 * j;
      if (node < N) {
        if (c0 < 64) *(float4*)(z + node * 64 + c0) = accs[j];
        else         *(float4*)(r + node * 64 + (c0 - 64)) = accs[j];
      }
    }
    __syncthreads();
  }
}

// ======== gather 2 + epilogue: float4 layout, sigmoid fused ========
__global__ __launch_bounds__(256) void k_gather2b(const float* __restrict__ z,
                                                  const float* __restrict__ r,
                                                  const float* __restrict__ b2,
                                                  const int* __restrict__ csr,
                                                  const int* __restrict__ row_start,
                                                  const int* __restrict__ cnt,
                                                  float* __restrict__ out, int N) {
  int wid = (blockIdx.x * blockDim.x + threadIdx.x) >> 6;
  int lane = threadIdx.x & 63;
  if (wid >= N) return;
  int egrp = lane >> 4, cq = lane & 15;
  const float4* z4 = (const float4*)z;
  int start = row_start[wid], c = cnt[wid], end = start + c;
  float4 acc = {0.f, 0.f, 0.f, 0.f};
  for (int j = start; j < end; j += 8) {
    int ea = j + egrp, eb = j + 4 + egrp;
    if (ea < end) {
      float4 va = z4[csr[ea] * 16 + cq];
      acc.x += va.x; acc.y += va.y; acc.z += va.z; acc.w += va.w;
    }
    if (eb < end) {
      float4 vb = z4[csr[eb] * 16 + cq];
      acc.x += vb.x; acc.y += vb.y; acc.z += vb.z; acc.w += vb.w;
    }
  }
  acc.x += __shfl_xor(acc.x, 32); acc.y += __shfl_xor(acc.y, 32);
  acc.z += __shfl_xor(acc.z, 32); acc.w += __shfl_xor(acc.w, 32);
  acc.x += __shfl_xor(acc.x, 16); acc.y += __shfl_xor(acc.y, 16);
  acc.z += __shfl_xor(acc.z, 16); acc.w += __shfl_xor(acc.w, 16);
  if (lane < 16) {
    float inv = 1.0f / fmaxf((float)c, 1.0f);
    float4 rv = ((const float4*)r)[wid * 16 + cq];
    float4 bv = ((const float4*)b2)[cq];
    float4 o;
    o.x = 1.0f / (1.0f + __expf(-(acc.x * inv + rv.x + bv.x)));
    o.y = 1.0f / (1.0f + __expf(-(acc.y * inv + rv.y + bv.y)));
    o.z = 1.0f / (1.0f + __expf(-(acc.z * inv + rv.z + bv.z)));
    o.w = 1.0f / (1.0f + __expf(-(acc.w * inv + rv.w + bv.w)));
    ((float4*)out)[wid * 16 + cq] = o;
  }
}

extern "C" void kernel_launch(void* const* d_in, const int* in_sizes, int n_in,
                              void* d_out, int out_size, void* d_ws, size_t ws_size,
                              hipStream_t stream) {
  const float* x   = (const float*)d_in[0];
  const int*   ei  = (const int*)d_in[1];
  const float* W1l = (const float*)d_in[2];
  const float* W1r = (const float*)d_in[3];
  const float* b1  = (const float*)d_in[4];
  const float* W2l = (const float*)d_in[5];
  const float* W2r = (const float*)d_in[6];
  const float* b2  = (const float*)d_in[7];
  float* out = (float*)d_out;

  int N = in_sizes[0] / IN_C;
  int E = in_sizes[1] / 2;
  const int* src = ei;
  const int* dst = ei + E;

  // ws: [bh 512][bstart 512][rstart 512][gcur 512][csr E][row_start N][cnt N]
  //     [agg N*64 f (ebuf ~3.3M ints aliases it)][z N*64][r N*64][h N*128]
  char* ws = (char*)d_ws;
  size_t off = 0;
  auto alignup = [](size_t v) { return (v + 511) & ~(size_t)511; };
  int* bh = (int*)(ws + off);         off = alignup(off + 512 * 4);
  int* bstart = (int*)(ws + off);     off = alignup(off + 512 * 4);
  int* rstart = (int*)(ws + off);     off = alignup(off + 512 * 4);
  int* gcur = (int*)(ws + off);       off = alignup(off + 512 * 4);
  int* csr = (int*)(ws + off);        off = alignup(off + (size_t)E * 4);
  int* row_start = (int*)(ws + off);  off = alignup(off + (size_t)N * 4);
  int* cnt = (int*)(ws + off);        off = alignup(off + (size_t)N * 4);
  float* aggbuf = (float*)(ws + off); off = alignup(off + (size_t)N * 64 * 4);
  float* zbuf = (float*)(ws + off);   off = alignup(off + (size_t)N * 64 * 4);
  float* rbuf = (float*)(ws + off);   off = alignup(off + (size_t)N * 64 * 4);
  float* hbuf = (float*)(ws + off);
  int* ebuf = (int*)aggbuf;  // ebuf (~13 MB) dead before k_gather1 writes aggbuf

  int NBUCK = (N + 255) >> 8;

  hipMemsetAsync(bh, 0, 512 * 4, stream);
  k_bhistL<<<256, 256, 0, stream>>>(dst, bh, E);
  k_bscan<<<1, 512, 0, stream>>>(bh, bstart, rstart, gcur);
  k_msplit<<<256, 256, 0, stream>>>(src, dst, gcur, ebuf, E);
  k_localcsr<<<NBUCK, 256, 0, stream>>>(ebuf, bstart, gcur, rstart, csr,
                                        row_start, cnt, N);

  k_gather1<<<(N + 3) / 4, 256, 0, stream>>>(x, csr, row_start, cnt, aggbuf, N);
  k_lin1<<<256, 512, 0, stream>>>(aggbuf, x, W1l, W1r, b1, hbuf, N);
  k_lin2<<<256, 512, 0, stream>>>(hbuf, W2l, W2r, zbuf, rbuf, N);
  k_gather2b<<<(N + 3) / 4, 256, 0, stream>>>(zbuf, rbuf, b2, csr, row_start, cnt,
                                              out, N);
}

// Round 8
// 437.746 us; speedup vs baseline: 4.2605x; 1.0018x over previous
//
#include <hip/hip_runtime.h>
#include <math.h>

#define IN_C 64
#define HID_C 128
#define OUT_C 64
// buckets of 256 nodes: bucket = dst >> 8; packed edge = (src<<8)|(dst&255)
// sentinel -1 is unreachable (src < 2^17, packed < 2^25)

__device__ __forceinline__ unsigned short f2bf(float f) {
  unsigned u = __float_as_uint(f);
  u = (u + 0x7FFFu + ((u >> 16) & 1u)) >> 16;  // RNE
  return (unsigned short)u;
}
__device__ __forceinline__ float bf2f(unsigned short h) {
  return __uint_as_float(((unsigned)h) << 16);
}
__device__ __forceinline__ unsigned pack2(float a, float b) {
  return (unsigned)f2bf(a) | ((unsigned)f2bf(b) << 16);
}

// ======== x -> bf16 copy for the gather (GEMM keeps fp32 x) ========
__global__ __launch_bounds__(256) void k_xcast(const float4* __restrict__ x4,
                                               uint2* __restrict__ xh2, int M) {
  for (int i = blockIdx.x * 256 + threadIdx.x; i < M; i += gridDim.x * 256) {
    float4 v = x4[i];
    uint2 p;
    p.x = pack2(v.x, v.y);
    p.y = pack2(v.z, v.w);
    xh2[i] = p;
  }
}

// ======== bhist: LDS-local 512-bin histogram, one merge add per bin ========
__global__ __launch_bounds__(256) void k_bhistL(const int* __restrict__ dst,
                                                int* __restrict__ bh, int E) {
  __shared__ int h[512];
  int t = threadIdx.x;
  h[t] = 0; h[t + 256] = 0;
  __syncthreads();
  for (int e = blockIdx.x * 256 + t; e < E; e += gridDim.x * 256)
    atomicAdd(&h[dst[e] >> 8], 1);
  __syncthreads();
  if (h[t]) atomicAdd(&bh[t], h[t]);
  if (h[t + 256]) atomicAdd(&bh[t + 256], h[t + 256]);
}

// ======== scan: chunked (slack) region starts + dense csr starts ========
__global__ __launch_bounds__(512) void k_bscan(const int* __restrict__ bh,
                                               int* __restrict__ bstart,
                                               int* __restrict__ rstart,
                                               int* __restrict__ gcur) {
  __shared__ int s1[512], s2[512];
  int t = threadIdx.x;
  int cnt = bh[t];
  int region = 16 * min(cnt, (cnt >> 4) + 256);
  s1[t] = region; s2[t] = cnt;
  __syncthreads();
  for (int off = 1; off < 512; off <<= 1) {
    int a1 = (t >= off) ? s1[t - off] : 0;
    int a2 = (t >= off) ? s2[t - off] : 0;
    __syncthreads();
    s1[t] += a1; s2[t] += a2;
    __syncthreads();
  }
  int ex1 = s1[t] - region;
  int ex2 = s2[t] - cnt;
  bstart[t] = ex1; gcur[t] = ex1; rstart[t] = ex2;
}

// ======== multisplit: LDS-buffered, 64B line-aligned single-owner flushes ====
__global__ __launch_bounds__(256) void k_msplit(const int* __restrict__ src,
                                                const int* __restrict__ dst,
                                                int* __restrict__ gcur,
                                                int* __restrict__ ebuf, int E) {
  __shared__ int bcnt[512];
  __shared__ __align__(16) int bins[512][32];
  int t = threadIdx.x;
  bcnt[t] = 0; bcnt[t + 256] = 0;
  int per = (E + gridDim.x - 1) / gridDim.x;
  int e0 = blockIdx.x * per, e1 = min(E, e0 + per);
  int e = e0 + t;
  int pb[2], pv[2]; int pc = 0;
  __syncthreads();
  for (;;) {
    if (pc < 2 && e < e1) {
      int d = dst[e], s = src[e];
      pb[pc] = d >> 8; pv[pc] = (s << 8) | (d & 255);
      pc++; e += 256;
    }
    for (int q = pc - 1; q >= 0; --q) {
      int pos = atomicAdd(&bcnt[pb[q]], 1);
      if (pos < 32) {
        bins[pb[q]][pos] = pv[q];
        pc--; pb[q] = pb[pc]; pv[q] = pv[pc];
      }
    }
    int pending = __syncthreads_count(pc > 0 || e < e1);
    for (int b = t; b < 512; b += 256) {
      int real = min(bcnt[b], 32);
      while (real >= 16) {
        int base = atomicAdd(&gcur[b], 16);
        int4* gout = (int4*)(ebuf + base);
        const int4* lb = (const int4*)(&bins[b][0]);
        gout[0] = lb[0]; gout[1] = lb[1]; gout[2] = lb[2]; gout[3] = lb[3];
        real -= 16;
        for (int k = 0; k < real; ++k) bins[b][k] = bins[b][k + 16];
      }
      bcnt[b] = real;
    }
    __syncthreads();
    if (!pending) break;
  }
  for (int b = t; b < 512; b += 256) {
    int realv = bcnt[b];
    if (realv > 0) {
      int base = atomicAdd(&gcur[b], 16);
#pragma unroll
      for (int k = 0; k < 16; ++k) ebuf[base + k] = (k < realv) ? bins[b][k] : -1;
    }
  }
}

// ======== per-bucket local CSR (256 nodes/bucket, skips sentinels) ========
__global__ __launch_bounds__(256) void k_localcsr(const int* __restrict__ ebuf,
                                                  const int* __restrict__ bstart,
                                                  const int* __restrict__ gcur,
                                                  const int* __restrict__ rstart,
                                                  int* __restrict__ csr,
                                                  int* __restrict__ row_start,
                                                  int* __restrict__ cnt, int N) {
  __shared__ int lcnt[256], loff[256], lcur[256];
  int t = threadIdx.x, b = blockIdx.x;
  int start = bstart[b], endp = gcur[b], rs = rstart[b];
  lcnt[t] = 0;
  __syncthreads();
  for (int i = start + t; i < endp; i += 256) {
    int pe = ebuf[i];
    if (pe != -1) atomicAdd(&lcnt[pe & 255], 1);
  }
  __syncthreads();
  int v = lcnt[t];
  loff[t] = v;
  __syncthreads();
  for (int off = 1; off < 256; off <<= 1) {
    int a = (t >= off) ? loff[t - off] : 0;
    __syncthreads();
    loff[t] += a;
    __syncthreads();
  }
  int ex = loff[t] - v;
  lcur[t] = ex;
  int node = (b << 8) + t;
  if (node < N) { row_start[node] = rs + ex; cnt[node] = v; }
  __syncthreads();
  for (int i = start + t; i < endp; i += 256) {
    int pe = ebuf[i];
    if (pe != -1) {
      int pos = atomicAdd(&lcur[pe & 255], 1);
      csr[rs + pos] = pe >> 8;
    }
  }
}

// ======== gather 1: bf16 x rows, wave/node, lane=(edge-group, chan-quad) ====
__global__ __launch_bounds__(256) void k_gather1(const unsigned short* __restrict__ xh,
                                                 const int* __restrict__ csr,
                                                 const int* __restrict__ row_start,
                                                 const int* __restrict__ cnt,
                                                 float* __restrict__ agg, int N) {
  int wid = (blockIdx.x * blockDim.x + threadIdx.x) >> 6;
  int lane = threadIdx.x & 63;
  if (wid >= N) return;
  int egrp = lane >> 4, cq = lane & 15;
  const uint2* xh2 = (const uint2*)xh;
  int start = row_start[wid], c = cnt[wid], end = start + c;
  float4 acc = {0.f, 0.f, 0.f, 0.f};
  for (int j = start; j < end; j += 8) {
    int ea = j + egrp, eb = j + 4 + egrp;
    if (ea < end) {
      uint2 v = xh2[csr[ea] * 16 + cq];
      acc.x += bf2f(v.x & 0xffff); acc.y += bf2f(v.x >> 16);
      acc.z += bf2f(v.y & 0xffff); acc.w += bf2f(v.y >> 16);
    }
    if (eb < end) {
      uint2 v = xh2[csr[eb] * 16 + cq];
      acc.x += bf2f(v.x & 0xffff); acc.y += bf2f(v.x >> 16);
      acc.z += bf2f(v.y & 0xffff); acc.w += bf2f(v.y >> 16);
    }
  }
  acc.x += __shfl_xor(acc.x, 32); acc.y += __shfl_xor(acc.y, 32);
  acc.z += __shfl_xor(acc.z, 32); acc.w += __shfl_xor(acc.w, 32);
  acc.x += __shfl_xor(acc.x, 16); acc.y += __shfl_xor(acc.y, 16);
  acc.z += __shfl_xor(acc.z, 16); acc.w += __shfl_xor(acc.w, 16);
  if (lane < 16) {
    float inv = 1.0f / fmaxf((float)c, 1.0f);
    float4 o = {acc.x * inv, acc.y * inv, acc.z * inv, acc.w * inv};
    ((float4*)agg)[wid * 16 + cq] = o;
  }
}

// ======== register-blocked fp32 GEMM kernels ========
#define FMA4(ACC, S, W4)                      \
  ACC.x = fmaf((S), (W4).x, ACC.x);           \
  ACC.y = fmaf((S), (W4).y, ACC.y);           \
  ACC.z = fmaf((S), (W4).z, ACC.z);           \
  ACC.w = fmaf((S), (W4).w, ACC.w);

__global__ __launch_bounds__(512) void k_lin1(
    const float* __restrict__ agg, const float* __restrict__ x,
    const float* __restrict__ W1l, const float* __restrict__ W1r,
    const float* __restrict__ b1, float* __restrict__ h, int N) {
  __shared__ __align__(16) float sW[128 * 132];
  __shared__ __align__(16) float sA[64 * 128];
  int t = threadIdx.x;
  for (int i = t; i < 64 * 128; i += 512) {
    int k = i & 63, c = i >> 6;
    sW[k * 132 + c] = W1l[i];
    sW[(k + 64) * 132 + c] = W1r[i];
  }
  int cg = t & 31, ng = t >> 5;
  int c0 = cg * 4;
  float4 bias = ((const float4*)b1)[cg];
  const float4* agg4 = (const float4*)agg;
  const float4* x4 = (const float4*)x;
  __syncthreads();

  int ntiles = (N + 63) >> 6;
  for (int tile = blockIdx.x; tile < ntiles; tile += gridDim.x) {
    int base = tile << 6;
#pragma unroll
    for (int j = 0; j < 4; ++j) {
      int idx = (t + j * 512) << 2;
      int n = idx >> 7, k = idx & 127;
      int node = base + n;
      float4 v = {0.f, 0.f, 0.f, 0.f};
      if (node < N) v = (k < 64) ? agg4[(node * 64 + k) >> 2]
                                 : x4[(node * 64 + (k - 64)) >> 2];
      *(float4*)(sA + n * 128 + k) = v;
    }
    __syncthreads();
    float4 acc0 = {0, 0, 0, 0}, acc1 = {0, 0, 0, 0}, acc2 = {0, 0, 0, 0}, acc3 = {0, 0, 0, 0};
#pragma unroll 4
    for (int k = 0; k < 128; k += 4) {
      float4 a0 = *(const float4*)(sA + (ng + 0) * 128 + k);
      float4 a1 = *(const float4*)(sA + (ng + 16) * 128 + k);
      float4 a2 = *(const float4*)(sA + (ng + 32) * 128 + k);
      float4 a3 = *(const float4*)(sA + (ng + 48) * 128 + k);
      float4 w0 = *(const float4*)(sW + (k + 0) * 132 + c0);
      float4 w1 = *(const float4*)(sW + (k + 1) * 132 + c0);
      float4 w2 = *(const float4*)(sW + (k + 2) * 132 + c0);
      float4 w3 = *(const float4*)(sW + (k + 3) * 132 + c0);
      FMA4(acc0, a0.x, w0) FMA4(acc1, a1.x, w0) FMA4(acc2, a2.x, w0) FMA4(acc3, a3.x, w0)
      FMA4(acc0, a0.y, w1) FMA4(acc1, a1.y, w1) FMA4(acc2, a2.y, w1) FMA4(acc3, a3.y, w1)
      FMA4(acc0, a0.z, w2) FMA4(acc1, a1.z, w2) FMA4(acc2, a2.z, w2) FMA4(acc3, a3.z, w2)
      FMA4(acc0, a0.w, w3) FMA4(acc1, a1.w, w3) FMA4(acc2, a2.w, w3) FMA4(acc3, a3.w, w3)
    }
    float4 accs[4] = {acc0, acc1, acc2, acc3};
#pragma unroll
    for (int j = 0; j < 4; ++j) {
      int node = base + ng + 16 * j;
      if (node < N) {
        float4 hv;
        hv.x = fmaxf(accs[j].x + bias.x, 0.f);
        hv.y = fmaxf(accs[j].y + bias.y, 0.f);
        hv.z = fmaxf(accs[j].z + bias.z, 0.f);
        hv.w = fmaxf(accs[j].w + bias.w, 0.f);
        *(float4*)(h + node * 128 + c0) = hv;
      }
    }
    __syncthreads();
  }
}

// layer 2: z(bf16) = h @ W2l^T, r(fp32) = h @ W2r^T
__global__ __launch_bounds__(512) void k_lin2(
    const float* __restrict__ h, const float* __restrict__ W2l,
    const float* __restrict__ W2r, unsigned short* __restrict__ zh,
    float* __restrict__ r, int N) {
  __shared__ __align__(16) float sW[128 * 132];
  __shared__ __align__(16) float sA[64 * 128];
  int t = threadIdx.x;
  for (int i = t; i < 64 * 128; i += 512) {
    int k = i & 127, c = i >> 7;
    sW[k * 132 + c] = W2l[i];
    sW[k * 132 + 64 + c] = W2r[i];
  }
  int cg = t & 31, ng = t >> 5;
  int c0 = cg * 4;
  const float4* h4 = (const float4*)h;
  __syncthreads();

  int ntiles = (N + 63) >> 6;
  for (int tile = blockIdx.x; tile < ntiles; tile += gridDim.x) {
    int base = tile << 6;
#pragma unroll
    for (int j = 0; j < 4; ++j) {
      int idx = (t + j * 512) << 2;
      int n = idx >> 7, k = idx & 127;
      int node = base + n;
      float4 v = {0.f, 0.f, 0.f, 0.f};
      if (node < N) v = h4[(node * 128 + k) >> 2];
      *(float4*)(sA + n * 128 + k) = v;
    }
    __syncthreads();
    float4 acc0 = {0, 0, 0, 0}, acc1 = {0, 0, 0, 0}, acc2 = {0, 0, 0, 0}, acc3 = {0, 0, 0, 0};
#pragma unroll 4
    for (int k = 0; k < 128; k += 4) {
      float4 a0 = *(const float4*)(sA + (ng + 0) * 128 + k);
      float4 a1 = *(const float4*)(sA + (ng + 16) * 128 + k);
      float4 a2 = *(const float4*)(sA + (ng + 32) * 128 + k);
      float4 a3 = *(const float4*)(sA + (ng + 48) * 128 + k);
      float4 w0 = *(const float4*)(sW + (k + 0) * 132 + c0);
      float4 w1 = *(const float4*)(sW + (k + 1) * 132 + c0);
      float4 w2 = *(const float4*)(sW + (k + 2) * 132 + c0);
      float4 w3 = *(const float4*)(sW + (k + 3) * 132 + c0);
      FMA4(acc0, a0.x, w0) FMA4(acc1, a1.x, w0) FMA4(acc2, a2.x, w0) FMA4(acc3, a3.x, w0)
      FMA4(acc0, a0.y, w1) FMA4(acc1, a1.y, w1) FMA4(acc2, a2.y, w1) FMA4(acc3, a3.y, w1)
      FMA4(acc0, a0.z, w2) FMA4(acc1, a1.z, w2) FMA4(acc2, a2.z, w2) FMA4(acc3, a3.z, w2)
      FMA4(acc0, a0.w, w3) FMA4(acc1, a1.w, w3) FMA4(acc2, a2.w, w3) FMA4(acc3, a3.w, w3)
    }
    float4 accs[4] = {acc0, acc1, acc2, acc3};
#pragma unroll
    for (int j = 0; j < 4; ++j) {
      int node = base + ng + 16 * j;
      if (node < N) {
        if (c0 < 64) {
          uint2 p;
          p.x = pack2(accs[j].x, accs[j].y);
          p.y = pack2(accs[j].z, accs[j].w);
          *(uint2*)(zh + node * 64 + c0) = p;
        } else {
          *(float4*)(r + node * 64 + (c0 - 64)) = accs[j];
        }
      }
    }
    __syncthreads();
  }
}

// ======== gather 2 + epilogue: bf16 z rows, sigmoid fused ========
__global__ __launch_bounds__(256) void k_gather2b(const unsigned short* __restrict__ zh,
                                                  const float* __restrict__ r,
                                                  const float* __restrict__ b2,
                                                  const int* __restrict__ csr,
                                                  const int* __restrict__ row_start,
                                                  const int* __restrict__ cnt,
                                                  float* __restrict__ out, int N) {
  int wid = (blockIdx.x * blockDim.x + threadIdx.x) >> 6;
  int lane = threadIdx.x & 63;
  if (wid >= N) return;
  int egrp = lane >> 4, cq = lane & 15;
  const uint2* zh2 = (const uint2*)zh;
  int start = row_start[wid], c = cnt[wid], end = start + c;
  float4 acc = {0.f, 0.f, 0.f, 0.f};
  for (int j = start; j < end; j += 8) {
    int ea = j + egrp, eb = j + 4 + egrp;
    if (ea < end) {
      uint2 v = zh2[csr[ea] * 16 + cq];
      acc.x += bf2f(v.x & 0xffff); acc.y += bf2f(v.x >> 16);
      acc.z += bf2f(v.y & 0xffff); acc.w += bf2f(v.y >> 16);
    }
    if (eb < end) {
      uint2 v = zh2[csr[eb] * 16 + cq];
      acc.x += bf2f(v.x & 0xffff); acc.y += bf2f(v.x >> 16);
      acc.z += bf2f(v.y & 0xffff); acc.w += bf2f(v.y >> 16);
    }
  }
  acc.x += __shfl_xor(acc.x, 32); acc.y += __shfl_xor(acc.y, 32);
  acc.z += __shfl_xor(acc.z, 32); acc.w += __shfl_xor(acc.w, 32);
  acc.x += __shfl_xor(acc.x, 16); acc.y += __shfl_xor(acc.y, 16);
  acc.z += __shfl_xor(acc.z, 16); acc.w += __shfl_xor(acc.w, 16);
  if (lane < 16) {
    float inv = 1.0f / fmaxf((float)c, 1.0f);
    float4 rv = ((const float4*)r)[wid * 16 + cq];
    float4 bv = ((const float4*)b2)[cq];
    float4 o;
    o.x = 1.0f / (1.0f + __expf(-(acc.x * inv + rv.x + bv.x)));
    o.y = 1.0f / (1.0f + __expf(-(acc.y * inv + rv.y + bv.y)));
    o.z = 1.0f / (1.0f + __expf(-(acc.z * inv + rv.z + bv.z)));
    o.w = 1.0f / (1.0f + __expf(-(acc.w * inv + rv.w + bv.w)));
    ((float4*)out)[wid * 16 + cq] = o;
  }
}

extern "C" void kernel_launch(void* const* d_in, const int* in_sizes, int n_in,
                              void* d_out, int out_size, void* d_ws, size_t ws_size,
                              hipStream_t stream) {
  const float* x   = (const float*)d_in[0];
  const int*   ei  = (const int*)d_in[1];
  const float* W1l = (const float*)d_in[2];
  const float* W1r = (const float*)d_in[3];
  const float* b1  = (const float*)d_in[4];
  const float* W2l = (const float*)d_in[5];
  const float* W2r = (const float*)d_in[6];
  const float* b2  = (const float*)d_in[7];
  float* out = (float*)d_out;

  int N = in_sizes[0] / IN_C;
  int E = in_sizes[1] / 2;
  const int* src = ei;
  const int* dst = ei + E;

  // ws: [bh 512][bstart 512][rstart 512][gcur 512][csr E][row_start N][cnt N]
  //     [xh N*64 bf16][zh N*64 bf16]
  //     [agg N*64 f (ebuf ~15MB aliases it)][r N*64 f][h N*128 f]
  char* ws = (char*)d_ws;
  size_t off = 0;
  auto alignup = [](size_t v) { return (v + 511) & ~(size_t)511; };
  int* bh = (int*)(ws + off);         off = alignup(off + 512 * 4);
  int* bstart = (int*)(ws + off);     off = alignup(off + 512 * 4);
  int* rstart = (int*)(ws + off);     off = alignup(off + 512 * 4);
  int* gcur = (int*)(ws + off);       off = alignup(off + 512 * 4);
  int* csr = (int*)(ws + off);        off = alignup(off + (size_t)E * 4);
  int* row_start = (int*)(ws + off);  off = alignup(off + (size_t)N * 4);
  int* cnt = (int*)(ws + off);        off = alignup(off + (size_t)N * 4);
  unsigned short* xh = (unsigned short*)(ws + off); off = alignup(off + (size_t)N * 64 * 2);
  unsigned short* zh = (unsigned short*)(ws + off); off = alignup(off + (size_t)N * 64 * 2);
  float* aggbuf = (float*)(ws + off); off = alignup(off + (size_t)N * 64 * 4);
  float* rbuf = (float*)(ws + off);   off = alignup(off + (size_t)N * 64 * 4);
  float* hbuf = (float*)(ws + off);
  int* ebuf = (int*)aggbuf;  // ebuf (~15 MB) dead before k_gather1 writes aggbuf

  int NBUCK = (N + 255) >> 8;

  hipMemsetAsync(bh, 0, 512 * 4, stream);
  k_xcast<<<2048, 256, 0, stream>>>((const float4*)x, (uint2*)xh, N * 16);
  k_bhistL<<<256, 256, 0, stream>>>(dst, bh, E);
  k_bscan<<<1, 512, 0, stream>>>(bh, bstart, rstart, gcur);
  k_msplit<<<256, 256, 0, stream>>>(src, dst, gcur, ebuf, E);
  k_localcsr<<<NBUCK, 256, 0, stream>>>(ebuf, bstart, gcur, rstart, csr,
                                        row_start, cnt, N);

  k_gather1<<<(N + 3) / 4, 256, 0, stream>>>(xh, csr, row_start, cnt, aggbuf, N);
  k_lin1<<<256, 512, 0, stream>>>(aggbuf, x, W1l, W1r, b1, hbuf, N);
  k_lin2<<<256, 512, 0, stream>>>(hbuf, W2l, W2r, zh, rbuf, N);
  k_gather2b<<<(N + 3) / 4, 256, 0, stream>>>(zh, rbuf, b2, csr, row_start, cnt,
                                              out, N);
}

// Round 9
// 370.347 us; speedup vs baseline: 5.0359x; 1.1820x over previous
//
#include <hip/hip_runtime.h>
#include <math.h>

#define IN_C 64
#define HID_C 128
#define OUT_C 64
// buckets of 256 nodes: bucket = dst >> 8; packed edge = (src<<8)|(dst&255)
// sentinel -1 is unreachable (src < 2^17, packed < 2^25)

typedef __attribute__((ext_vector_type(8))) short bf16x8;   // 8 bf16 (4 VGPRs)
typedef __attribute__((ext_vector_type(4))) float f32x4;    // mfma C/D

__device__ __forceinline__ unsigned short f2bf(float f) {
  unsigned u = __float_as_uint(f);
  u = (u + 0x7FFFu + ((u >> 16) & 1u)) >> 16;  // RNE
  return (unsigned short)u;
}
__device__ __forceinline__ float bf2f(unsigned short h) {
  return __uint_as_float(((unsigned)h) << 16);
}
__device__ __forceinline__ unsigned pack2(float a, float b) {
  return (unsigned)f2bf(a) | ((unsigned)f2bf(b) << 16);
}

// ======== x -> bf16 copy for gather1 + lin1 ========
__global__ __launch_bounds__(256) void k_xcast(const float4* __restrict__ x4,
                                               uint2* __restrict__ xh2, int M) {
  for (int i = blockIdx.x * 256 + threadIdx.x; i < M; i += gridDim.x * 256) {
    float4 v = x4[i];
    uint2 p;
    p.x = pack2(v.x, v.y);
    p.y = pack2(v.z, v.w);
    xh2[i] = p;
  }
}

// ======== bhist: LDS-local 512-bin histogram ========
__global__ __launch_bounds__(256) void k_bhistL(const int* __restrict__ dst,
                                                int* __restrict__ bh, int E) {
  __shared__ int h[512];
  int t = threadIdx.x;
  h[t] = 0; h[t + 256] = 0;
  __syncthreads();
  for (int e = blockIdx.x * 256 + t; e < E; e += gridDim.x * 256)
    atomicAdd(&h[dst[e] >> 8], 1);
  __syncthreads();
  if (h[t]) atomicAdd(&bh[t], h[t]);
  if (h[t + 256]) atomicAdd(&bh[t + 256], h[t + 256]);
}

// ======== scan: chunked (slack) region starts + dense csr starts ========
__global__ __launch_bounds__(512) void k_bscan(const int* __restrict__ bh,
                                               int* __restrict__ bstart,
                                               int* __restrict__ rstart,
                                               int* __restrict__ gcur) {
  __shared__ int s1[512], s2[512];
  int t = threadIdx.x;
  int cnt = bh[t];
  int region = 16 * min(cnt, (cnt >> 4) + 256);
  s1[t] = region; s2[t] = cnt;
  __syncthreads();
  for (int off = 1; off < 512; off <<= 1) {
    int a1 = (t >= off) ? s1[t - off] : 0;
    int a2 = (t >= off) ? s2[t - off] : 0;
    __syncthreads();
    s1[t] += a1; s2[t] += a2;
    __syncthreads();
  }
  int ex1 = s1[t] - region;
  int ex2 = s2[t] - cnt;
  bstart[t] = ex1; gcur[t] = ex1; rstart[t] = ex2;
}

// ======== multisplit: LDS-buffered, 64B line-aligned single-owner flushes ====
__global__ __launch_bounds__(256) void k_msplit(const int* __restrict__ src,
                                                const int* __restrict__ dst,
                                                int* __restrict__ gcur,
                                                int* __restrict__ ebuf, int E) {
  __shared__ int bcnt[512];
  __shared__ __align__(16) int bins[512][32];
  int t = threadIdx.x;
  bcnt[t] = 0; bcnt[t + 256] = 0;
  int per = (E + gridDim.x - 1) / gridDim.x;
  int e0 = blockIdx.x * per, e1 = min(E, e0 + per);
  int e = e0 + t;
  int pb[2], pv[2]; int pc = 0;
  __syncthreads();
  for (;;) {
    if (pc < 2 && e < e1) {
      int d = dst[e], s = src[e];
      pb[pc] = d >> 8; pv[pc] = (s << 8) | (d & 255);
      pc++; e += 256;
    }
    for (int q = pc - 1; q >= 0; --q) {
      int pos = atomicAdd(&bcnt[pb[q]], 1);
      if (pos < 32) {
        bins[pb[q]][pos] = pv[q];
        pc--; pb[q] = pb[pc]; pv[q] = pv[pc];
      }
    }
    int pending = __syncthreads_count(pc > 0 || e < e1);
    for (int b = t; b < 512; b += 256) {
      int real = min(bcnt[b], 32);
      while (real >= 16) {
        int base = atomicAdd(&gcur[b], 16);
        int4* gout = (int4*)(ebuf + base);
        const int4* lb = (const int4*)(&bins[b][0]);
        gout[0] = lb[0]; gout[1] = lb[1]; gout[2] = lb[2]; gout[3] = lb[3];
        real -= 16;
        for (int k = 0; k < real; ++k) bins[b][k] = bins[b][k + 16];
      }
      bcnt[b] = real;
    }
    __syncthreads();
    if (!pending) break;
  }
  for (int b = t; b < 512; b += 256) {
    int realv = bcnt[b];
    if (realv > 0) {
      int base = atomicAdd(&gcur[b], 16);
#pragma unroll
      for (int k = 0; k < 16; ++k) ebuf[base + k] = (k < realv) ? bins[b][k] : -1;
    }
  }
}

// ======== per-bucket local CSR (256 nodes/bucket, skips sentinels) ========
__global__ __launch_bounds__(256) void k_localcsr(const int* __restrict__ ebuf,
                                                  const int* __restrict__ bstart,
                                                  const int* __restrict__ gcur,
                                                  const int* __restrict__ rstart,
                                                  int* __restrict__ csr,
                                                  int* __restrict__ row_start,
                                                  int* __restrict__ cnt, int N) {
  __shared__ int lcnt[256], loff[256], lcur[256];
  int t = threadIdx.x, b = blockIdx.x;
  int start = bstart[b], endp = gcur[b], rs = rstart[b];
  lcnt[t] = 0;
  __syncthreads();
  for (int i = start + t; i < endp; i += 256) {
    int pe = ebuf[i];
    if (pe != -1) atomicAdd(&lcnt[pe & 255], 1);
  }
  __syncthreads();
  int v = lcnt[t];
  loff[t] = v;
  __syncthreads();
  for (int off = 1; off < 256; off <<= 1) {
    int a = (t >= off) ? loff[t - off] : 0;
    __syncthreads();
    loff[t] += a;
    __syncthreads();
  }
  int ex = loff[t] - v;
  lcur[t] = ex;
  int node = (b << 8) + t;
  if (node < N) { row_start[node] = rs + ex; cnt[node] = v; }
  __syncthreads();
  for (int i = start + t; i < endp; i += 256) {
    int pe = ebuf[i];
    if (pe != -1) {
      int pos = atomicAdd(&lcur[pe & 255], 1);
      csr[rs + pos] = pe >> 8;
    }
  }
}

// ======== gather 1: bf16 x rows -> bf16 agg rows ========
__global__ __launch_bounds__(256) void k_gather1(const unsigned short* __restrict__ xh,
                                                 const int* __restrict__ csr,
                                                 const int* __restrict__ row_start,
                                                 const int* __restrict__ cnt,
                                                 unsigned short* __restrict__ aggh,
                                                 int N) {
  int wid = (blockIdx.x * blockDim.x + threadIdx.x) >> 6;
  int lane = threadIdx.x & 63;
  if (wid >= N) return;
  int egrp = lane >> 4, cq = lane & 15;
  const uint2* xh2 = (const uint2*)xh;
  int start = row_start[wid], c = cnt[wid], end = start + c;
  float4 acc = {0.f, 0.f, 0.f, 0.f};
  for (int j = start; j < end; j += 8) {
    int ea = j + egrp, eb = j + 4 + egrp;
    if (ea < end) {
      uint2 v = xh2[csr[ea] * 16 + cq];
      acc.x += bf2f(v.x & 0xffff); acc.y += bf2f(v.x >> 16);
      acc.z += bf2f(v.y & 0xffff); acc.w += bf2f(v.y >> 16);
    }
    if (eb < end) {
      uint2 v = xh2[csr[eb] * 16 + cq];
      acc.x += bf2f(v.x & 0xffff); acc.y += bf2f(v.x >> 16);
      acc.z += bf2f(v.y & 0xffff); acc.w += bf2f(v.y >> 16);
    }
  }
  acc.x += __shfl_xor(acc.x, 32); acc.y += __shfl_xor(acc.y, 32);
  acc.z += __shfl_xor(acc.z, 32); acc.w += __shfl_xor(acc.w, 32);
  acc.x += __shfl_xor(acc.x, 16); acc.y += __shfl_xor(acc.y, 16);
  acc.z += __shfl_xor(acc.z, 16); acc.w += __shfl_xor(acc.w, 16);
  if (lane < 16) {
    float inv = 1.0f / fmaxf((float)c, 1.0f);
    uint2 p;
    p.x = pack2(acc.x * inv, acc.y * inv);
    p.y = pack2(acc.z * inv, acc.w * inv);
    ((uint2*)aggh)[wid * 16 + cq] = p;
  }
}

// ======== MFMA bf16 GEMM, layer 1: h(bf16) = relu([agg|x]@[W1l|W1r]^T + b1) ===
// 256 thr = 4 waves; 64-node tile; wave w: nodes [16w,16w+16), all 128 ch.
// sW[o][k] 128x136 bf16 (pad->2-way LDS aliasing, free); sA[n][k] 64x136 bf16.
// Frag layouts (m89/m91/m120-verified): A[m=lane&15][k=quad*8+j];
// B = 8 contiguous k of W row (o0+lane&15); C/D col=lane&15,row=quad*4+reg.
__global__ __launch_bounds__(256, 3) void k_lin1(
    const unsigned short* __restrict__ aggh, const unsigned short* __restrict__ xh,
    const float* __restrict__ W1l, const float* __restrict__ W1r,
    const float* __restrict__ b1, unsigned short* __restrict__ h, int N) {
  __shared__ __align__(16) unsigned short sW[128 * 136];
  __shared__ __align__(16) unsigned short sA[64 * 136];
  __shared__ float sb[128];
  int t = threadIdx.x;
  for (int i = t; i < 128 * 128; i += 256) {
    int o = i >> 7, k = i & 127;
    float w = (k < 64) ? W1l[o * 64 + k] : W1r[o * 64 + (k - 64)];
    sW[o * 136 + k] = f2bf(w);
  }
  if (t < 128) sb[t] = b1[t];
  int lane = t & 63, qm = lane >> 4, ln = lane & 15;
  int m0 = (t >> 6) * 16;
  __syncthreads();

  int ntiles = (N + 63) >> 6;
  for (int tile = blockIdx.x; tile < ntiles; tile += gridDim.x) {
    int base = tile << 6;
    for (int u = t; u < 64 * 64; u += 256) {  // 4096 uints = 64 nodes x 64 uint
      int n = u >> 6, uu = u & 63;
      int node = base + n;
      unsigned v = 0;
      if (node < N) v = (uu < 32) ? ((const unsigned*)aggh)[node * 32 + uu]
                                  : ((const unsigned*)xh)[node * 32 + (uu - 32)];
      ((unsigned*)(sA + n * 136))[uu] = v;
    }
    __syncthreads();
    bf16x8 af[4];
#pragma unroll
    for (int kc = 0; kc < 4; ++kc)
      af[kc] = *(const bf16x8*)(sA + (m0 + ln) * 136 + kc * 32 + qm * 8);
#pragma unroll
    for (int ot = 0; ot < 8; ++ot) {
      int o0 = ot * 16;
      f32x4 acc = {0.f, 0.f, 0.f, 0.f};
#pragma unroll
      for (int kc = 0; kc < 4; ++kc) {
        bf16x8 bfr = *(const bf16x8*)(sW + (o0 + ln) * 136 + kc * 32 + qm * 8);
        acc = __builtin_amdgcn_mfma_f32_16x16x32_bf16(af[kc], bfr, acc, 0, 0, 0);
      }
      int col = o0 + ln;
      float bias = sb[col];
#pragma unroll
      for (int i = 0; i < 4; ++i) {
        int node = base + m0 + qm * 4 + i;
        if (node < N) h[node * 128 + col] = f2bf(fmaxf(acc[i] + bias, 0.f));
      }
    }
    __syncthreads();
  }
}

// ======== MFMA bf16 GEMM, layer 2: z(bf16)=h@W2l^T, r(fp32)=h@W2r^T ========
__global__ __launch_bounds__(256, 3) void k_lin2(
    const unsigned short* __restrict__ h, const float* __restrict__ W2l,
    const float* __restrict__ W2r, unsigned short* __restrict__ zh,
    float* __restrict__ r, int N) {
  __shared__ __align__(16) unsigned short sW[128 * 136];
  __shared__ __align__(16) unsigned short sA[64 * 136];
  int t = threadIdx.x;
  for (int i = t; i < 128 * 128; i += 256) {
    int u = i >> 7, k = i & 127;
    float w = (u < 64) ? W2l[u * 128 + k] : W2r[(u - 64) * 128 + k];
    sW[u * 136 + k] = f2bf(w);
  }
  int lane = t & 63, qm = lane >> 4, ln = lane & 15;
  int m0 = (t >> 6) * 16;
  __syncthreads();

  int ntiles = (N + 63) >> 6;
  for (int tile = blockIdx.x; tile < ntiles; tile += gridDim.x) {
    int base = tile << 6;
    for (int u = t; u < 64 * 64; u += 256) {
      int n = u >> 6, uu = u & 63;
      int node = base + n;
      unsigned v = 0;
      if (node < N) v = ((const unsigned*)h)[node * 64 + uu];
      ((unsigned*)(sA + n * 136))[uu] = v;
    }
    __syncthreads();
    bf16x8 af[4];
#pragma unroll
    for (int kc = 0; kc < 4; ++kc)
      af[kc] = *(const bf16x8*)(sA + (m0 + ln) * 136 + kc * 32 + qm * 8);
#pragma unroll
    for (int ot = 0; ot < 8; ++ot) {
      int o0 = ot * 16;
      f32x4 acc = {0.f, 0.f, 0.f, 0.f};
#pragma unroll
      for (int kc = 0; kc < 4; ++kc) {
        bf16x8 bfr = *(const bf16x8*)(sW + (o0 + ln) * 136 + kc * 32 + qm * 8);
        acc = __builtin_amdgcn_mfma_f32_16x16x32_bf16(af[kc], bfr, acc, 0, 0, 0);
      }
      int u = o0 + ln;  // u<64: z channel; u>=64: r channel u-64
#pragma unroll
      for (int i = 0; i < 4; ++i) {
        int node = base + m0 + qm * 4 + i;
        if (node < N) {
          if (u < 64) zh[node * 64 + u] = f2bf(acc[i]);
          else        r[node * 64 + (u - 64)] = acc[i];
        }
      }
    }
    __syncthreads();
  }
}

// ======== gather 2 + epilogue: bf16 z rows, sigmoid fused ========
__global__ __launch_bounds__(256) void k_gather2b(const unsigned short* __restrict__ zh,
                                                  const float* __restrict__ r,
                                                  const float* __restrict__ b2,
                                                  const int* __restrict__ csr,
                                                  const int* __restrict__ row_start,
                                                  const int* __restrict__ cnt,
                                                  float* __restrict__ out, int N) {
  int wid = (blockIdx.x * blockDim.x + threadIdx.x) >> 6;
  int lane = threadIdx.x & 63;
  if (wid >= N) return;
  int egrp = lane >> 4, cq = lane & 15;
  const uint2* zh2 = (const uint2*)zh;
  int start = row_start[wid], c = cnt[wid], end = start + c;
  float4 acc = {0.f, 0.f, 0.f, 0.f};
  for (int j = start; j < end; j += 8) {
    int ea = j + egrp, eb = j + 4 + egrp;
    if (ea < end) {
      uint2 v = zh2[csr[ea] * 16 + cq];
      acc.x += bf2f(v.x & 0xffff); acc.y += bf2f(v.x >> 16);
      acc.z += bf2f(v.y & 0xffff); acc.w += bf2f(v.y >> 16);
    }
    if (eb < end) {
      uint2 v = zh2[csr[eb] * 16 + cq];
      acc.x += bf2f(v.x & 0xffff); acc.y += bf2f(v.x >> 16);
      acc.z += bf2f(v.y & 0xffff); acc.w += bf2f(v.y >> 16);
    }
  }
  acc.x += __shfl_xor(acc.x, 32); acc.y += __shfl_xor(acc.y, 32);
  acc.z += __shfl_xor(acc.z, 32); acc.w += __shfl_xor(acc.w, 32);
  acc.x += __shfl_xor(acc.x, 16); acc.y += __shfl_xor(acc.y, 16);
  acc.z += __shfl_xor(acc.z, 16); acc.w += __shfl_xor(acc.w, 16);
  if (lane < 16) {
    float inv = 1.0f / fmaxf((float)c, 1.0f);
    float4 rv = ((const float4*)r)[wid * 16 + cq];
    float4 bv = ((const float4*)b2)[cq];
    float4 o;
    o.x = 1.0f / (1.0f + __expf(-(acc.x * inv + rv.x + bv.x)));
    o.y = 1.0f / (1.0f + __expf(-(acc.y * inv + rv.y + bv.y)));
    o.z = 1.0f / (1.0f + __expf(-(acc.z * inv + rv.z + bv.z)));
    o.w = 1.0f / (1.0f + __expf(-(acc.w * inv + rv.w + bv.w)));
    ((float4*)out)[wid * 16 + cq] = o;
  }
}

extern "C" void kernel_launch(void* const* d_in, const int* in_sizes, int n_in,
                              void* d_out, int out_size, void* d_ws, size_t ws_size,
                              hipStream_t stream) {
  const float* x   = (const float*)d_in[0];
  const int*   ei  = (const int*)d_in[1];
  const float* W1l = (const float*)d_in[2];
  const float* W1r = (const float*)d_in[3];
  const float* b1  = (const float*)d_in[4];
  const float* W2l = (const float*)d_in[5];
  const float* W2r = (const float*)d_in[6];
  const float* b2  = (const float*)d_in[7];
  float* out = (float*)d_out;

  int N = in_sizes[0] / IN_C;
  int E = in_sizes[1] / 2;
  const int* src = ei;
  const int* dst = ei + E;

  // ws: [bh 512][bstart 512][rstart 512][gcur 512][csr E][row_start N][cnt N]
  //     [xh N*64 bf16][aggh N*64 bf16][zh N*64 bf16]  (ebuf ~15MB aliases aggh+zh)
  //     [r N*64 f][h N*128 bf16]
  char* ws = (char*)d_ws;
  size_t off = 0;
  auto alignup = [](size_t v) { return (v + 511) & ~(size_t)511; };
  int* bh = (int*)(ws + off);         off = alignup(off + 512 * 4);
  int* bstart = (int*)(ws + off);     off = alignup(off + 512 * 4);
  int* rstart = (int*)(ws + off);     off = alignup(off + 512 * 4);
  int* gcur = (int*)(ws + off);       off = alignup(off + 512 * 4);
  int* csr = (int*)(ws + off);        off = alignup(off + (size_t)E * 4);
  int* row_start = (int*)(ws + off);  off = alignup(off + (size_t)N * 4);
  int* cnt = (int*)(ws + off);        off = alignup(off + (size_t)N * 4);
  unsigned short* xh = (unsigned short*)(ws + off);   off = alignup(off + (size_t)N * 64 * 2);
  unsigned short* aggh = (unsigned short*)(ws + off); off = alignup(off + (size_t)N * 64 * 2);
  unsigned short* zh = (unsigned short*)(ws + off);   off = alignup(off + (size_t)N * 64 * 2);
  float* rbuf = (float*)(ws + off);   off = alignup(off + (size_t)N * 64 * 4);
  unsigned short* hbuf = (unsigned short*)(ws + off);
  int* ebuf = (int*)aggh;  // spans aggh+zh (25.6MB >= ~15MB chunked region); dead
                           // before k_gather1 writes aggh / k_lin2 writes zh

  int NBUCK = (N + 255) >> 8;

  hipMemsetAsync(bh, 0, 512 * 4, stream);
  k_xcast<<<2048, 256, 0, stream>>>((const float4*)x, (uint2*)xh, N * 16);
  k_bhistL<<<256, 256, 0, stream>>>(dst, bh, E);
  k_bscan<<<1, 512, 0, stream>>>(bh, bstart, rstart, gcur);
  k_msplit<<<256, 256, 0, stream>>>(src, dst, gcur, ebuf, E);
  k_localcsr<<<NBUCK, 256, 0, stream>>>(ebuf, bstart, gcur, rstart, csr,
                                        row_start, cnt, N);

  k_gather1<<<(N + 3) / 4, 256, 0, stream>>>(xh, csr, row_start, cnt, aggh, N);
  k_lin1<<<768, 256, 0, stream>>>(aggh, xh, W1l, W1r, b1, hbuf, N);
  k_lin2<<<768, 256, 0, stream>>>(hbuf, W2l, W2r, zh, rbuf, N);
  k_gather2b<<<(N + 3) / 4, 256, 0, stream>>>(zh, rbuf, b2, csr, row_start, cnt,
                                              out, N);
}

// Round 10
// 336.940 us; speedup vs baseline: 5.5352x; 1.0991x over previous
//
#include <hip/hip_runtime.h>
#include <math.h>

#define IN_C 64
#define HID_C 128
#define OUT_C 64
// buckets of 256 nodes: bucket = dst >> 8; packed edge = (src<<8)|(dst&255)
// sentinel -1 unreachable (src <= N < 2^17). CSR rows padded to 8-multiples
// with dummy src = N (row N of xh/zh is zeroed) -> branch-free gather loops.

typedef __attribute__((ext_vector_type(8))) short bf16x8;   // 8 bf16 (4 VGPRs)
typedef __attribute__((ext_vector_type(4))) float f32x4;    // mfma C/D

__device__ __forceinline__ unsigned short f2bf(float f) {
  unsigned u = __float_as_uint(f);
  u = (u + 0x7FFFu + ((u >> 16) & 1u)) >> 16;  // RNE
  return (unsigned short)u;
}
__device__ __forceinline__ float bf2f(unsigned v) {  // low 16 bits = bf16
  return __uint_as_float(v << 16);
}
__device__ __forceinline__ unsigned pack2(float a, float b) {
  return (unsigned)f2bf(a) | ((unsigned)f2bf(b) << 16);
}

// ======== x -> bf16 (rows 0..N-1) + zero dummy row N ========
__global__ __launch_bounds__(256) void k_xcast(const float4* __restrict__ x4,
                                               uint2* __restrict__ xh2,
                                               int Mreal, int Mtot) {
  for (int i = blockIdx.x * 256 + threadIdx.x; i < Mtot; i += gridDim.x * 256) {
    uint2 p = {0u, 0u};
    if (i < Mreal) {
      float4 v = x4[i];
      p.x = pack2(v.x, v.y);
      p.y = pack2(v.z, v.w);
    }
    xh2[i] = p;
  }
}

// ======== bhist: LDS-local 512-bin histogram ========
__global__ __launch_bounds__(256) void k_bhistL(const int* __restrict__ dst,
                                                int* __restrict__ bh, int E) {
  __shared__ int h[512];
  int t = threadIdx.x;
  h[t] = 0; h[t + 256] = 0;
  __syncthreads();
  for (int e = blockIdx.x * 256 + t; e < E; e += gridDim.x * 256)
    atomicAdd(&h[dst[e] >> 8], 1);
  __syncthreads();
  if (h[t]) atomicAdd(&bh[t], h[t]);
  if (h[t + 256]) atomicAdd(&bh[t + 256], h[t + 256]);
}

// ======== scan: ebuf chunked-region starts + padded csr starts ========
// ebuf region: 16*min(cnt, cnt/16+256) (256 writer blocks, 1 residual each).
// csr region: cnt + 2048 (pad <= 8 per node * 256 nodes/bucket).
__global__ __launch_bounds__(512) void k_bscan(const int* __restrict__ bh,
                                               int* __restrict__ bstart,
                                               int* __restrict__ rstart,
                                               int* __restrict__ gcur) {
  __shared__ int s1[512], s2[512];
  int t = threadIdx.x;
  int cnt = bh[t];
  int region = 16 * min(cnt, (cnt >> 4) + 256);
  int creg = cnt + 2048;
  s1[t] = region; s2[t] = creg;
  __syncthreads();
  for (int off = 1; off < 512; off <<= 1) {
    int a1 = (t >= off) ? s1[t - off] : 0;
    int a2 = (t >= off) ? s2[t - off] : 0;
    __syncthreads();
    s1[t] += a1; s2[t] += a2;
    __syncthreads();
  }
  int ex1 = s1[t] - region;
  int ex2 = s2[t] - creg;
  bstart[t] = ex1; gcur[t] = ex1; rstart[t] = ex2;
}

// ======== multisplit: LDS-buffered, 64B line-aligned single-owner flushes ====
__global__ __launch_bounds__(256) void k_msplit(const int* __restrict__ src,
                                                const int* __restrict__ dst,
                                                int* __restrict__ gcur,
                                                int* __restrict__ ebuf, int E) {
  __shared__ int bcnt[512];
  __shared__ __align__(16) int bins[512][32];
  int t = threadIdx.x;
  bcnt[t] = 0; bcnt[t + 256] = 0;
  int per = (E + gridDim.x - 1) / gridDim.x;
  int e0 = blockIdx.x * per, e1 = min(E, e0 + per);
  int e = e0 + t;
  int pb[2], pv[2]; int pc = 0;
  __syncthreads();
  for (;;) {
    if (pc < 2 && e < e1) {
      int d = dst[e], s = src[e];
      pb[pc] = d >> 8; pv[pc] = (s << 8) | (d & 255);
      pc++; e += 256;
    }
    for (int q = pc - 1; q >= 0; --q) {
      int pos = atomicAdd(&bcnt[pb[q]], 1);
      if (pos < 32) {
        bins[pb[q]][pos] = pv[q];
        pc--; pb[q] = pb[pc]; pv[q] = pv[pc];
      }
    }
    int pending = __syncthreads_count(pc > 0 || e < e1);
    for (int b = t; b < 512; b += 256) {
      int real = min(bcnt[b], 32);
      while (real >= 16) {
        int base = atomicAdd(&gcur[b], 16);
        int4* gout = (int4*)(ebuf + base);
        const int4* lb = (const int4*)(&bins[b][0]);
        gout[0] = lb[0]; gout[1] = lb[1]; gout[2] = lb[2]; gout[3] = lb[3];
        real -= 16;
        for (int k = 0; k < real; ++k) bins[b][k] = bins[b][k + 16];
      }
      bcnt[b] = real;
    }
    __syncthreads();
    if (!pending) break;
  }
  for (int b = t; b < 512; b += 256) {
    int realv = bcnt[b];
    if (realv > 0) {
      int base = atomicAdd(&gcur[b], 16);
#pragma unroll
      for (int k = 0; k < 16; ++k) ebuf[base + k] = (k < realv) ? bins[b][k] : -1;
    }
  }
}

// ======== per-bucket local CSR, 8-padded rows, emits row_start/rend/invd ====
__global__ __launch_bounds__(256) void k_localcsr(const int* __restrict__ ebuf,
                                                  const int* __restrict__ bstart,
                                                  const int* __restrict__ gcur,
                                                  const int* __restrict__ rstart,
                                                  int* __restrict__ csr,
                                                  int* __restrict__ row_start,
                                                  int* __restrict__ rend,
                                                  float* __restrict__ invd, int N) {
  __shared__ int lcnt[256], loff[256], lcur[256];
  int t = threadIdx.x, b = blockIdx.x;
  int start = bstart[b], endp = gcur[b], rs = rstart[b];
  lcnt[t] = 0;
  __syncthreads();
  for (int i = start + t; i < endp; i += 256) {
    int pe = ebuf[i];
    if (pe != -1) atomicAdd(&lcnt[pe & 255], 1);
  }
  __syncthreads();
  int v = lcnt[t];
  int pvn = (v + 7) & ~7;  // padded row length
  loff[t] = pvn;
  __syncthreads();
  for (int off = 1; off < 256; off <<= 1) {
    int a = (t >= off) ? loff[t - off] : 0;
    __syncthreads();
    loff[t] += a;
    __syncthreads();
  }
  int ex = loff[t] - pvn;
  lcur[t] = ex;
  int node = (b << 8) + t;
  if (node < N) {
    row_start[node] = rs + ex;
    rend[node] = rs + ex + pvn;
    invd[node] = 1.0f / fmaxf((float)v, 1.0f);
  }
  __syncthreads();
  for (int i = start + t; i < endp; i += 256) {
    int pe = ebuf[i];
    if (pe != -1) {
      int pos = atomicAdd(&lcur[pe & 255], 1);
      csr[rs + pos] = pe >> 8;
    }
  }
  // fill pad slots with dummy src N (zero row)
  for (int k = ex + v; k < ex + pvn; ++k) csr[rs + k] = N;
}

// ======== gather 1: branch-free, 8-lane x uint4 rows, bf16 in/out ========
__global__ __launch_bounds__(256) void k_gather1(const uint4* __restrict__ xh4,
                                                 const int* __restrict__ csr,
                                                 const int* __restrict__ row_start,
                                                 const int* __restrict__ rend,
                                                 const float* __restrict__ invd,
                                                 uint4* __restrict__ aggh4, int N) {
  int wid = (blockIdx.x * blockDim.x + threadIdx.x) >> 6;
  int lane = threadIdx.x & 63;
  if (wid >= N) return;
  int rq = lane >> 3, cq = lane & 7;
  int j = row_start[wid], end = rend[wid];
  float a0 = 0, a1 = 0, a2 = 0, a3 = 0, a4 = 0, a5 = 0, a6 = 0, a7 = 0;
#pragma unroll 2
  for (; j < end; j += 8) {
    int s = csr[j + rq];
    uint4 v = xh4[s * 8 + cq];
    a0 += bf2f(v.x & 0xffffu); a1 += bf2f(v.x >> 16);
    a2 += bf2f(v.y & 0xffffu); a3 += bf2f(v.y >> 16);
    a4 += bf2f(v.z & 0xffffu); a5 += bf2f(v.z >> 16);
    a6 += bf2f(v.w & 0xffffu); a7 += bf2f(v.w >> 16);
  }
#define RED8(d)                                               \
  a0 += __shfl_xor(a0, d); a1 += __shfl_xor(a1, d);           \
  a2 += __shfl_xor(a2, d); a3 += __shfl_xor(a3, d);           \
  a4 += __shfl_xor(a4, d); a5 += __shfl_xor(a5, d);           \
  a6 += __shfl_xor(a6, d); a7 += __shfl_xor(a7, d);
  RED8(8) RED8(16) RED8(32)
  if (rq == 0) {
    float inv = invd[wid];
    uint4 p;
    p.x = pack2(a0 * inv, a1 * inv);
    p.y = pack2(a2 * inv, a3 * inv);
    p.z = pack2(a4 * inv, a5 * inv);
    p.w = pack2(a6 * inv, a7 * inv);
    aggh4[wid * 8 + cq] = p;
  }
}

// ======== MFMA bf16 GEMM, layer 1: h(bf16) = relu([agg|x]@[W1l|W1r]^T + b1) ===
__global__ __launch_bounds__(256, 3) void k_lin1(
    const unsigned short* __restrict__ aggh, const unsigned short* __restrict__ xh,
    const float* __restrict__ W1l, const float* __restrict__ W1r,
    const float* __restrict__ b1, unsigned short* __restrict__ h, int N) {
  __shared__ __align__(16) unsigned short sW[128 * 136];
  __shared__ __align__(16) unsigned short sA[64 * 136];
  __shared__ float sb[128];
  int t = threadIdx.x;
  for (int i = t; i < 128 * 128; i += 256) {
    int o = i >> 7, k = i & 127;
    float w = (k < 64) ? W1l[o * 64 + k] : W1r[o * 64 + (k - 64)];
    sW[o * 136 + k] = f2bf(w);
  }
  if (t < 128) sb[t] = b1[t];
  int lane = t & 63, qm = lane >> 4, ln = lane & 15;
  int m0 = (t >> 6) * 16;
  __syncthreads();

  int ntiles = (N + 63) >> 6;
  for (int tile = blockIdx.x; tile < ntiles; tile += gridDim.x) {
    int base = tile << 6;
    for (int u = t; u < 64 * 64; u += 256) {
      int n = u >> 6, uu = u & 63;
      int node = base + n;
      unsigned v = 0;
      if (node < N) v = (uu < 32) ? ((const unsigned*)aggh)[node * 32 + uu]
                                  : ((const unsigned*)xh)[node * 32 + (uu - 32)];
      ((unsigned*)(sA + n * 136))[uu] = v;
    }
    __syncthreads();
    bf16x8 af[4];
#pragma unroll
    for (int kc = 0; kc < 4; ++kc)
      af[kc] = *(const bf16x8*)(sA + (m0 + ln) * 136 + kc * 32 + qm * 8);
#pragma unroll
    for (int ot = 0; ot < 8; ++ot) {
      int o0 = ot * 16;
      f32x4 acc = {0.f, 0.f, 0.f, 0.f};
#pragma unroll
      for (int kc = 0; kc < 4; ++kc) {
        bf16x8 bfr = *(const bf16x8*)(sW + (o0 + ln) * 136 + kc * 32 + qm * 8);
        acc = __builtin_amdgcn_mfma_f32_16x16x32_bf16(af[kc], bfr, acc, 0, 0, 0);
      }
      int col = o0 + ln;
      float bias = sb[col];
#pragma unroll
      for (int i = 0; i < 4; ++i) {
        int node = base + m0 + qm * 4 + i;
        if (node < N) h[node * 128 + col] = f2bf(fmaxf(acc[i] + bias, 0.f));
      }
    }
    __syncthreads();
  }
}

// ======== MFMA bf16 GEMM, layer 2: z(bf16)=h@W2l^T, r(fp32)=h@W2r^T + b2 ====
// Also zeroes dummy z row N (block 0).
__global__ __launch_bounds__(256, 3) void k_lin2(
    const unsigned short* __restrict__ h, const float* __restrict__ W2l,
    const float* __restrict__ W2r, const float* __restrict__ b2,
    unsigned short* __restrict__ zh, float* __restrict__ r, int N) {
  __shared__ __align__(16) unsigned short sW[128 * 136];
  __shared__ __align__(16) unsigned short sA[64 * 136];
  __shared__ float sb2[64];
  int t = threadIdx.x;
  if (blockIdx.x == 0 && t < 32) ((unsigned*)zh)[N * 32 + t] = 0;
  for (int i = t; i < 128 * 128; i += 256) {
    int u = i >> 7, k = i & 127;
    float w = (u < 64) ? W2l[u * 128 + k] : W2r[(u - 64) * 128 + k];
    sW[u * 136 + k] = f2bf(w);
  }
  if (t < 64) sb2[t] = b2[t];
  int lane = t & 63, qm = lane >> 4, ln = lane & 15;
  int m0 = (t >> 6) * 16;
  __syncthreads();

  int ntiles = (N + 63) >> 6;
  for (int tile = blockIdx.x; tile < ntiles; tile += gridDim.x) {
    int base = tile << 6;
    for (int u = t; u < 64 * 64; u += 256) {
      int n = u >> 6, uu = u & 63;
      int node = base + n;
      unsigned v = 0;
      if (node < N) v = ((const unsigned*)h)[node * 64 + uu];
      ((unsigned*)(sA + n * 136))[uu] = v;
    }
    __syncthreads();
    bf16x8 af[4];
#pragma unroll
    for (int kc = 0; kc < 4; ++kc)
      af[kc] = *(const bf16x8*)(sA + (m0 + ln) * 136 + kc * 32 + qm * 8);
#pragma unroll
    for (int ot = 0; ot < 8; ++ot) {
      int o0 = ot * 16;
      f32x4 acc = {0.f, 0.f, 0.f, 0.f};
#pragma unroll
      for (int kc = 0; kc < 4; ++kc) {
        bf16x8 bfr = *(const bf16x8*)(sW + (o0 + ln) * 136 + kc * 32 + qm * 8);
        acc = __builtin_amdgcn_mfma_f32_16x16x32_bf16(af[kc], bfr, acc, 0, 0, 0);
      }
      int u = o0 + ln;  // u<64: z channel; u>=64: r channel u-64 (bias folded)
#pragma unroll
      for (int i = 0; i < 4; ++i) {
        int node = base + m0 + qm * 4 + i;
        if (node < N) {
          if (u < 64) zh[node * 64 + u] = f2bf(acc[i]);
          else        r[node * 64 + (u - 64)] = acc[i] + sb2[u - 64];
        }
      }
    }
    __syncthreads();
  }
}

// ======== gather 2 + epilogue: branch-free, 8-lane rows, sigmoid fused ======
__global__ __launch_bounds__(256) void k_gather2b(const uint4* __restrict__ zh4,
                                                  const float* __restrict__ r,
                                                  const int* __restrict__ csr,
                                                  const int* __restrict__ row_start,
                                                  const int* __restrict__ rend,
                                                  const float* __restrict__ invd,
                                                  float* __restrict__ out, int N) {
  int wid = (blockIdx.x * blockDim.x + threadIdx.x) >> 6;
  int lane = threadIdx.x & 63;
  if (wid >= N) return;
  int rq = lane >> 3, cq = lane & 7;
  int j = row_start[wid], end = rend[wid];
  float a0 = 0, a1 = 0, a2 = 0, a3 = 0, a4 = 0, a5 = 0, a6 = 0, a7 = 0;
#pragma unroll 2
  for (; j < end; j += 8) {
    int s = csr[j + rq];
    uint4 v = zh4[s * 8 + cq];
    a0 += bf2f(v.x & 0xffffu); a1 += bf2f(v.x >> 16);
    a2 += bf2f(v.y & 0xffffu); a3 += bf2f(v.y >> 16);
    a4 += bf2f(v.z & 0xffffu); a5 += bf2f(v.z >> 16);
    a6 += bf2f(v.w & 0xffffu); a7 += bf2f(v.w >> 16);
  }
  RED8(8) RED8(16) RED8(32)
  if (rq == 0) {
    float inv = invd[wid];
    const float4* r4 = (const float4*)r;
    float4 rv0 = r4[wid * 16 + cq * 2];
    float4 rv1 = r4[wid * 16 + cq * 2 + 1];
    float4 o0, o1;
    o0.x = 1.0f / (1.0f + __expf(-(a0 * inv + rv0.x)));
    o0.y = 1.0f / (1.0f + __expf(-(a1 * inv + rv0.y)));
    o0.z = 1.0f / (1.0f + __expf(-(a2 * inv + rv0.z)));
    o0.w = 1.0f / (1.0f + __expf(-(a3 * inv + rv0.w)));
    o1.x = 1.0f / (1.0f + __expf(-(a4 * inv + rv1.x)));
    o1.y = 1.0f / (1.0f + __expf(-(a5 * inv + rv1.y)));
    o1.z = 1.0f / (1.0f + __expf(-(a6 * inv + rv1.z)));
    o1.w = 1.0f / (1.0f + __expf(-(a7 * inv + rv1.w)));
    float4* out4 = (float4*)out;
    out4[wid * 16 + cq * 2] = o0;
    out4[wid * 16 + cq * 2 + 1] = o1;
  }
}

extern "C" void kernel_launch(void* const* d_in, const int* in_sizes, int n_in,
                              void* d_out, int out_size, void* d_ws, size_t ws_size,
                              hipStream_t stream) {
  const float* x   = (const float*)d_in[0];
  const int*   ei  = (const int*)d_in[1];
  const float* W1l = (const float*)d_in[2];
  const float* W1r = (const float*)d_in[3];
  const float* b1  = (const float*)d_in[4];
  const float* W2l = (const float*)d_in[5];
  const float* W2r = (const float*)d_in[6];
  const float* b2  = (const float*)d_in[7];
  float* out = (float*)d_out;

  int N = in_sizes[0] / IN_C;
  int E = in_sizes[1] / 2;
  const int* src = ei;
  const int* dst = ei + E;

  // ws: [bh 512][bstart 512][rstart 512][gcur 512][csr E+512*2048]
  //     [row_start N][rend N][invd N]
  //     [xh (N+1)*64 bf16][aggh N*64 bf16][zh (N+1)*64 bf16]  (ebuf aliases aggh+zh)
  //     [r N*64 f][h N*128 bf16]
  char* ws = (char*)d_ws;
  size_t off = 0;
  auto alignup = [](size_t v) { return (v + 511) & ~(size_t)511; };
  int* bh = (int*)(ws + off);         off = alignup(off + 512 * 4);
  int* bstart = (int*)(ws + off);     off = alignup(off + 512 * 4);
  int* rstart = (int*)(ws + off);     off = alignup(off + 512 * 4);
  int* gcur = (int*)(ws + off);       off = alignup(off + 512 * 4);
  int* csr = (int*)(ws + off);        off = alignup(off + ((size_t)E + 512 * 2048) * 4);
  int* row_start = (int*)(ws + off);  off = alignup(off + (size_t)N * 4);
  int* rend = (int*)(ws + off);       off = alignup(off + (size_t)N * 4);
  float* invd = (float*)(ws + off);   off = alignup(off + (size_t)N * 4);
  unsigned short* xh = (unsigned short*)(ws + off);   off = alignup(off + (size_t)(N + 1) * 64 * 2);
  unsigned short* aggh = (unsigned short*)(ws + off); off = alignup(off + (size_t)N * 64 * 2);
  unsigned short* zh = (unsigned short*)(ws + off);   off = alignup(off + (size_t)(N + 1) * 64 * 2);
  float* rbuf = (float*)(ws + off);   off = alignup(off + (size_t)N * 64 * 4);
  unsigned short* hbuf = (unsigned short*)(ws + off);
  int* ebuf = (int*)aggh;  // spans aggh+zh (~25.6MB >= ~14.8MB chunked region);
                           // dead before k_gather1 writes aggh / k_lin2 writes zh

  hipMemsetAsync(bh, 0, 512 * 4, stream);
  k_xcast<<<2048, 256, 0, stream>>>((const float4*)x, (uint2*)xh, N * 16, (N + 1) * 16);
  k_bhistL<<<1024, 256, 0, stream>>>(dst, bh, E);
  k_bscan<<<1, 512, 0, stream>>>(bh, bstart, rstart, gcur);
  k_msplit<<<256, 256, 0, stream>>>(src, dst, gcur, ebuf, E);
  k_localcsr<<<512, 256, 0, stream>>>(ebuf, bstart, gcur, rstart, csr,
                                      row_start, rend, invd, N);

  k_gather1<<<(N + 3) / 4, 256, 0, stream>>>((const uint4*)xh, csr, row_start,
                                             rend, invd, (uint4*)aggh, N);
  k_lin1<<<768, 256, 0, stream>>>(aggh, xh, W1l, W1r, b1, hbuf, N);
  k_lin2<<<768, 256, 0, stream>>>(hbuf, W2l, W2r, b2, zh, rbuf, N);
  k_gather2b<<<(N + 3) / 4, 256, 0, stream>>>((const uint4*)zh, rbuf, csr,
                                              row_start, rend, invd, out, N);
}

// Round 11
// 330.973 us; speedup vs baseline: 5.6349x; 1.0180x over previous
//
#include <hip/hip_runtime.h>
#include <math.h>

#define IN_C 64
#define HID_C 128
#define OUT_C 64
#define NBK 256   // buckets of 512 nodes: bucket = dst >> 9
#define BD 64     // msplit bin ring depth
// packed edge = (src<<9)|(dst&511); sentinel -1 unreachable (src <= N < 2^17).
// CSR rows padded to 8-multiples with dummy src = N (row N of xh/zh zeroed).

typedef __attribute__((ext_vector_type(8))) short bf16x8;   // 8 bf16 (4 VGPRs)
typedef __attribute__((ext_vector_type(4))) float f32x4;    // mfma C/D

__device__ __forceinline__ unsigned short f2bf(float f) {
  unsigned u = __float_as_uint(f);
  u = (u + 0x7FFFu + ((u >> 16) & 1u)) >> 16;  // RNE
  return (unsigned short)u;
}
__device__ __forceinline__ float bf2f(unsigned v) {  // low 16 bits = bf16
  return __uint_as_float(v << 16);
}
__device__ __forceinline__ unsigned pack2(float a, float b) {
  return (unsigned)f2bf(a) | ((unsigned)f2bf(b) << 16);
}

// ======== x -> bf16 (rows 0..N-1) + zero dummy row N ========
__global__ __launch_bounds__(256) void k_xcast(const float4* __restrict__ x4,
                                               uint2* __restrict__ xh2,
                                               int Mreal, int Mtot) {
  for (int i = blockIdx.x * 256 + threadIdx.x; i < Mtot; i += gridDim.x * 256) {
    uint2 p = {0u, 0u};
    if (i < Mreal) {
      float4 v = x4[i];
      p.x = pack2(v.x, v.y);
      p.y = pack2(v.z, v.w);
    }
    xh2[i] = p;
  }
}

// ======== bhist: LDS-local 256-bin histogram ========
__global__ __launch_bounds__(256) void k_bhistL(const int* __restrict__ dst,
                                                int* __restrict__ bh, int E) {
  __shared__ int h[NBK];
  int t = threadIdx.x;
  h[t] = 0;
  __syncthreads();
  for (int e = blockIdx.x * 256 + t; e < E; e += gridDim.x * 256)
    atomicAdd(&h[dst[e] >> 9], 1);
  __syncthreads();
  if (h[t]) atomicAdd(&bh[t], h[t]);
}

// ======== scan: ebuf chunked-region starts + padded csr starts ========
// ebuf region: 16*min(cnt, cnt/16+512) (512 writer blocks, <=1 residual each).
// csr region: cnt + 4096 (pad <= 8 per node * 512 nodes/bucket).
__global__ __launch_bounds__(256) void k_bscan(const int* __restrict__ bh,
                                               int* __restrict__ bstart,
                                               int* __restrict__ rstart,
                                               int* __restrict__ gcur) {
  __shared__ int s1[NBK], s2[NBK];
  int t = threadIdx.x;
  int cnt = bh[t];
  int region = 16 * min(cnt, (cnt >> 4) + 512);
  int creg = cnt + 4096;
  s1[t] = region; s2[t] = creg;
  __syncthreads();
  for (int off = 1; off < NBK; off <<= 1) {
    int a1 = (t >= off) ? s1[t - off] : 0;
    int a2 = (t >= off) ? s2[t - off] : 0;
    __syncthreads();
    s1[t] += a1; s2[t] += a2;
    __syncthreads();
  }
  int ex1 = s1[t] - region;
  int ex2 = s2[t] - creg;
  bstart[t] = ex1; gcur[t] = ex1; rstart[t] = ex2;
}

// ======== multisplit: transposed ring bins, 64B single-owner flushes ========
// bins[slot][bucket]: bank = bucket%32 -> scatter spreads, owner-flush 2-way.
// Ring head removes shift copies. 2-fetch/iter halves barrier rounds.
__global__ __launch_bounds__(256) void k_msplit(const int* __restrict__ src,
                                                const int* __restrict__ dst,
                                                int* __restrict__ gcur,
                                                int* __restrict__ ebuf, int E) {
  __shared__ int bcnt[NBK], bhead[NBK];
  __shared__ int bins[BD][NBK];
  int t = threadIdx.x;
  bcnt[t] = 0; bhead[t] = 0;
  int per = (E + gridDim.x - 1) / gridDim.x;
  int e0 = blockIdx.x * per, e1 = min(E, e0 + per);
  int e = e0 + t;
  int pb[2], pv[2]; int pc = 0;
  __syncthreads();
  for (;;) {
    // fetch up to 2 edges, then try to place pending
    while (pc < 2 && e < e1) {
      int d = dst[e], s = src[e];
      pb[pc] = d >> 9; pv[pc] = (s << 9) | (d & 511);
      pc++; e += 256;
    }
    for (int q = pc - 1; q >= 0; --q) {
      int pos = atomicAdd(&bcnt[pb[q]], 1);
      if (pos < BD) {
        bins[(bhead[pb[q]] + pos) & (BD - 1)][pb[q]] = pv[q];
        pc--;
        if (q != pc) { pb[q] = pb[pc]; pv[q] = pv[pc]; }
      }
    }
    int pending = __syncthreads_count(pc > 0 || e < e1);
    // flush: thread t owns bucket t
    int cntv = min(bcnt[t], BD);
    int head = bhead[t];
    while (cntv >= 16) {
      int base = atomicAdd(&gcur[t], 16);
      int4 o[4];
#pragma unroll
      for (int k = 0; k < 16; ++k)
        ((int*)o)[k] = bins[(head + k) & (BD - 1)][t];
      int4* g = (int4*)(ebuf + base);
      g[0] = o[0]; g[1] = o[1]; g[2] = o[2]; g[3] = o[3];
      head = (head + 16) & (BD - 1);
      cntv -= 16;
    }
    bhead[t] = head;
    bcnt[t] = cntv;
    __syncthreads();
    if (!pending) break;
  }
  // residual: one sentinel-padded chunk per non-empty bucket
  int cntv = bcnt[t];
  if (cntv > 0) {
    int head = bhead[t];
    int base = atomicAdd(&gcur[t], 16);
#pragma unroll
    for (int k = 0; k < 16; ++k)
      ebuf[base + k] = (k < cntv) ? bins[(head + k) & (BD - 1)][t] : -1;
  }
}

// ======== per-bucket local CSR (512 nodes/bucket), 8-padded rows ========
__global__ __launch_bounds__(512) void k_localcsr(const int* __restrict__ ebuf,
                                                  const int* __restrict__ bstart,
                                                  const int* __restrict__ gcur,
                                                  const int* __restrict__ rstart,
                                                  int* __restrict__ csr,
                                                  int* __restrict__ row_start,
                                                  int* __restrict__ rend,
                                                  float* __restrict__ invd, int N) {
  __shared__ int lcnt[512], loff[512], lcur[512];
  int t = threadIdx.x, b = blockIdx.x;
  int start = bstart[b], endp = gcur[b], rs = rstart[b];
  lcnt[t] = 0;
  __syncthreads();
  for (int i = start + t; i < endp; i += 512) {
    int pe = ebuf[i];
    if (pe != -1) atomicAdd(&lcnt[pe & 511], 1);
  }
  __syncthreads();
  int v = lcnt[t];
  int pvn = (v + 7) & ~7;  // padded row length
  loff[t] = pvn;
  __syncthreads();
  for (int off = 1; off < 512; off <<= 1) {
    int a = (t >= off) ? loff[t - off] : 0;
    __syncthreads();
    loff[t] += a;
    __syncthreads();
  }
  int ex = loff[t] - pvn;
  lcur[t] = ex;
  int node = (b << 9) + t;
  if (node < N) {
    row_start[node] = rs + ex;
    rend[node] = rs + ex + pvn;
    invd[node] = 1.0f / fmaxf((float)v, 1.0f);
  }
  __syncthreads();
  for (int i = start + t; i < endp; i += 512) {
    int pe = ebuf[i];
    if (pe != -1) {
      int pos = atomicAdd(&lcur[pe & 511], 1);
      csr[rs + pos] = pe >> 9;
    }
  }
  for (int k = ex + v; k < ex + pvn; ++k) csr[rs + k] = N;
}

// ======== gather 1: branch-free, 8-lane x uint4 rows, bf16 in/out ========
__global__ __launch_bounds__(256) void k_gather1(const uint4* __restrict__ xh4,
                                                 const int* __restrict__ csr,
                                                 const int* __restrict__ row_start,
                                                 const int* __restrict__ rend,
                                                 const float* __restrict__ invd,
                                                 uint4* __restrict__ aggh4, int N) {
  int wid = (blockIdx.x * blockDim.x + threadIdx.x) >> 6;
  int lane = threadIdx.x & 63;
  if (wid >= N) return;
  int rq = lane >> 3, cq = lane & 7;
  int j = row_start[wid], end = rend[wid];
  float a0 = 0, a1 = 0, a2 = 0, a3 = 0, a4 = 0, a5 = 0, a6 = 0, a7 = 0;
#pragma unroll 2
  for (; j < end; j += 8) {
    int s = csr[j + rq];
    uint4 v = xh4[s * 8 + cq];
    a0 += bf2f(v.x & 0xffffu); a1 += bf2f(v.x >> 16);
    a2 += bf2f(v.y & 0xffffu); a3 += bf2f(v.y >> 16);
    a4 += bf2f(v.z & 0xffffu); a5 += bf2f(v.z >> 16);
    a6 += bf2f(v.w & 0xffffu); a7 += bf2f(v.w >> 16);
  }
#define RED8(d)                                               \
  a0 += __shfl_xor(a0, d); a1 += __shfl_xor(a1, d);           \
  a2 += __shfl_xor(a2, d); a3 += __shfl_xor(a3, d);           \
  a4 += __shfl_xor(a4, d); a5 += __shfl_xor(a5, d);           \
  a6 += __shfl_xor(a6, d); a7 += __shfl_xor(a7, d);
  RED8(8) RED8(16) RED8(32)
  if (rq == 0) {
    float inv = invd[wid];
    uint4 p;
    p.x = pack2(a0 * inv, a1 * inv);
    p.y = pack2(a2 * inv, a3 * inv);
    p.z = pack2(a4 * inv, a5 * inv);
    p.w = pack2(a6 * inv, a7 * inv);
    aggh4[wid * 8 + cq] = p;
  }
}

// ======== MFMA bf16 GEMM, layer 1: h(bf16) = relu([agg|x]@[W1l|W1r]^T + b1) ===
__global__ __launch_bounds__(256, 3) void k_lin1(
    const unsigned short* __restrict__ aggh, const unsigned short* __restrict__ xh,
    const float* __restrict__ W1l, const float* __restrict__ W1r,
    const float* __restrict__ b1, unsigned short* __restrict__ h, int N) {
  __shared__ __align__(16) unsigned short sW[128 * 136];
  __shared__ __align__(16) unsigned short sA[64 * 136];
  __shared__ float sb[128];
  int t = threadIdx.x;
  for (int i = t; i < 128 * 128; i += 256) {
    int o = i >> 7, k = i & 127;
    float w = (k < 64) ? W1l[o * 64 + k] : W1r[o * 64 + (k - 64)];
    sW[o * 136 + k] = f2bf(w);
  }
  if (t < 128) sb[t] = b1[t];
  int lane = t & 63, qm = lane >> 4, ln = lane & 15;
  int m0 = (t >> 6) * 16;
  __syncthreads();

  int ntiles = (N + 63) >> 6;
  for (int tile = blockIdx.x; tile < ntiles; tile += gridDim.x) {
    int base = tile << 6;
    for (int u = t; u < 64 * 64; u += 256) {
      int n = u >> 6, uu = u & 63;
      int node = base + n;
      unsigned v = 0;
      if (node < N) v = (uu < 32) ? ((const unsigned*)aggh)[node * 32 + uu]
                                  : ((const unsigned*)xh)[node * 32 + (uu - 32)];
      ((unsigned*)(sA + n * 136))[uu] = v;
    }
    __syncthreads();
    bf16x8 af[4];
#pragma unroll
    for (int kc = 0; kc < 4; ++kc)
      af[kc] = *(const bf16x8*)(sA + (m0 + ln) * 136 + kc * 32 + qm * 8);
#pragma unroll
    for (int ot = 0; ot < 8; ++ot) {
      int o0 = ot * 16;
      f32x4 acc = {0.f, 0.f, 0.f, 0.f};
#pragma unroll
      for (int kc = 0; kc < 4; ++kc) {
        bf16x8 bfr = *(const bf16x8*)(sW + (o0 + ln) * 136 + kc * 32 + qm * 8);
        acc = __builtin_amdgcn_mfma_f32_16x16x32_bf16(af[kc], bfr, acc, 0, 0, 0);
      }
      int col = o0 + ln;
      float bias = sb[col];
#pragma unroll
      for (int i = 0; i < 4; ++i) {
        int node = base + m0 + qm * 4 + i;
        if (node < N) h[node * 128 + col] = f2bf(fmaxf(acc[i] + bias, 0.f));
      }
    }
    __syncthreads();
  }
}

// ======== MFMA bf16 GEMM, layer 2: z(bf16)=h@W2l^T, r(fp32)=h@W2r^T + b2 ====
__global__ __launch_bounds__(256, 3) void k_lin2(
    const unsigned short* __restrict__ h, const float* __restrict__ W2l,
    const float* __restrict__ W2r, const float* __restrict__ b2,
    unsigned short* __restrict__ zh, float* __restrict__ r, int N) {
  __shared__ __align__(16) unsigned short sW[128 * 136];
  __shared__ __align__(16) unsigned short sA[64 * 136];
  __shared__ float sb2[64];
  int t = threadIdx.x;
  if (blockIdx.x == 0 && t < 32) ((unsigned*)zh)[N * 32 + t] = 0;
  for (int i = t; i < 128 * 128; i += 256) {
    int u = i >> 7, k = i & 127;
    float w = (u < 64) ? W2l[u * 128 + k] : W2r[(u - 64) * 128 + k];
    sW[u * 136 + k] = f2bf(w);
  }
  if (t < 64) sb2[t] = b2[t];
  int lane = t & 63, qm = lane >> 4, ln = lane & 15;
  int m0 = (t >> 6) * 16;
  __syncthreads();

  int ntiles = (N + 63) >> 6;
  for (int tile = blockIdx.x; tile < ntiles; tile += gridDim.x) {
    int base = tile << 6;
    for (int u = t; u < 64 * 64; u += 256) {
      int n = u >> 6, uu = u & 63;
      int node = base + n;
      unsigned v = 0;
      if (node < N) v = ((const unsigned*)h)[node * 64 + uu];
      ((unsigned*)(sA + n * 136))[uu] = v;
    }
    __syncthreads();
    bf16x8 af[4];
#pragma unroll
    for (int kc = 0; kc < 4; ++kc)
      af[kc] = *(const bf16x8*)(sA + (m0 + ln) * 136 + kc * 32 + qm * 8);
#pragma unroll
    for (int ot = 0; ot < 8; ++ot) {
      int o0 = ot * 16;
      f32x4 acc = {0.f, 0.f, 0.f, 0.f};
#pragma unroll
      for (int kc = 0; kc < 4; ++kc) {
        bf16x8 bfr = *(const bf16x8*)(sW + (o0 + ln) * 136 + kc * 32 + qm * 8);
        acc = __builtin_amdgcn_mfma_f32_16x16x32_bf16(af[kc], bfr, acc, 0, 0, 0);
      }
      int u = o0 + ln;  // u<64: z channel; u>=64: r channel u-64 (bias folded)
#pragma unroll
      for (int i = 0; i < 4; ++i) {
        int node = base + m0 + qm * 4 + i;
        if (node < N) {
          if (u < 64) zh[node * 64 + u] = f2bf(acc[i]);
          else        r[node * 64 + (u - 64)] = acc[i] + sb2[u - 64];
        }
      }
    }
    __syncthreads();
  }
}

// ======== gather 2 + epilogue: branch-free, 8-lane rows, sigmoid fused ======
__global__ __launch_bounds__(256) void k_gather2b(const uint4* __restrict__ zh4,
                                                  const float* __restrict__ r,
                                                  const int* __restrict__ csr,
                                                  const int* __restrict__ row_start,
                                                  const int* __restrict__ rend,
                                                  const float* __restrict__ invd,
                                                  float* __restrict__ out, int N) {
  int wid = (blockIdx.x * blockDim.x + threadIdx.x) >> 6;
  int lane = threadIdx.x & 63;
  if (wid >= N) return;
  int rq = lane >> 3, cq = lane & 7;
  int j = row_start[wid], end = rend[wid];
  float a0 = 0, a1 = 0, a2 = 0, a3 = 0, a4 = 0, a5 = 0, a6 = 0, a7 = 0;
#pragma unroll 2
  for (; j < end; j += 8) {
    int s = csr[j + rq];
    uint4 v = zh4[s * 8 + cq];
    a0 += bf2f(v.x & 0xffffu); a1 += bf2f(v.x >> 16);
    a2 += bf2f(v.y & 0xffffu); a3 += bf2f(v.y >> 16);
    a4 += bf2f(v.z & 0xffffu); a5 += bf2f(v.z >> 16);
    a6 += bf2f(v.w & 0xffffu); a7 += bf2f(v.w >> 16);
  }
  RED8(8) RED8(16) RED8(32)
  if (rq == 0) {
    float inv = invd[wid];
    const float4* r4 = (const float4*)r;
    float4 rv0 = r4[wid * 16 + cq * 2];
    float4 rv1 = r4[wid * 16 + cq * 2 + 1];
    float4 o0, o1;
    o0.x = 1.0f / (1.0f + __expf(-(a0 * inv + rv0.x)));
    o0.y = 1.0f / (1.0f + __expf(-(a1 * inv + rv0.y)));
    o0.z = 1.0f / (1.0f + __expf(-(a2 * inv + rv0.z)));
    o0.w = 1.0f / (1.0f + __expf(-(a3 * inv + rv0.w)));
    o1.x = 1.0f / (1.0f + __expf(-(a4 * inv + rv1.x)));
    o1.y = 1.0f / (1.0f + __expf(-(a5 * inv + rv1.y)));
    o1.z = 1.0f / (1.0f + __expf(-(a6 * inv + rv1.z)));
    o1.w = 1.0f / (1.0f + __expf(-(a7 * inv + rv1.w)));
    float4* out4 = (float4*)out;
    out4[wid * 16 + cq * 2] = o0;
    out4[wid * 16 + cq * 2 + 1] = o1;
  }
}

extern "C" void kernel_launch(void* const* d_in, const int* in_sizes, int n_in,
                              void* d_out, int out_size, void* d_ws, size_t ws_size,
                              hipStream_t stream) {
  const float* x   = (const float*)d_in[0];
  const int*   ei  = (const int*)d_in[1];
  const float* W1l = (const float*)d_in[2];
  const float* W1r = (const float*)d_in[3];
  const float* b1  = (const float*)d_in[4];
  const float* W2l = (const float*)d_in[5];
  const float* W2r = (const float*)d_in[6];
  const float* b2  = (const float*)d_in[7];
  float* out = (float*)d_out;

  int N = in_sizes[0] / IN_C;
  int E = in_sizes[1] / 2;
  const int* src = ei;
  const int* dst = ei + E;

  // ws: [bh 256][bstart 256][rstart 256][gcur 256][csr E+256*4096]
  //     [row_start N][rend N][invd N]
  //     [xh (N+1)*64 bf16][aggh N*64 bf16][zh (N+1)*64 bf16]  (ebuf aliases aggh+zh)
  //     [r N*64 f][h N*128 bf16]
  char* ws = (char*)d_ws;
  size_t off = 0;
  auto alignup = [](size_t v) { return (v + 511) & ~(size_t)511; };
  int* bh = (int*)(ws + off);         off = alignup(off + NBK * 4);
  int* bstart = (int*)(ws + off);     off = alignup(off + NBK * 4);
  int* rstart = (int*)(ws + off);     off = alignup(off + NBK * 4);
  int* gcur = (int*)(ws + off);       off = alignup(off + NBK * 4);
  int* csr = (int*)(ws + off);        off = alignup(off + ((size_t)E + NBK * 4096) * 4);
  int* row_start = (int*)(ws + off);  off = alignup(off + (size_t)N * 4);
  int* rend = (int*)(ws + off);       off = alignup(off + (size_t)N * 4);
  float* invd = (float*)(ws + off);   off = alignup(off + (size_t)N * 4);
  unsigned short* xh = (unsigned short*)(ws + off);   off = alignup(off + (size_t)(N + 1) * 64 * 2);
  unsigned short* aggh = (unsigned short*)(ws + off); off = alignup(off + (size_t)N * 64 * 2);
  unsigned short* zh = (unsigned short*)(ws + off);   off = alignup(off + (size_t)(N + 1) * 64 * 2);
  float* rbuf = (float*)(ws + off);   off = alignup(off + (size_t)N * 64 * 4);
  unsigned short* hbuf = (unsigned short*)(ws + off);
  int* ebuf = (int*)aggh;  // spans aggh+zh (~25.6MB >= 14.8MB worst-case chunked
                           // region); dead before k_gather1 / k_lin2 write them

  hipMemsetAsync(bh, 0, NBK * 4, stream);
  k_xcast<<<2048, 256, 0, stream>>>((const float4*)x, (uint2*)xh, N * 16, (N + 1) * 16);
  k_bhistL<<<1024, 256, 0, stream>>>(dst, bh, E);
  k_bscan<<<1, NBK, 0, stream>>>(bh, bstart, rstart, gcur);
  k_msplit<<<512, 256, 0, stream>>>(src, dst, gcur, ebuf, E);
  k_localcsr<<<NBK, 512, 0, stream>>>(ebuf, bstart, gcur, rstart, csr,
                                      row_start, rend, invd, N);

  k_gather1<<<(N + 3) / 4, 256, 0, stream>>>((const uint4*)xh, csr, row_start,
                                             rend, invd, (uint4*)aggh, N);
  k_lin1<<<768, 256, 0, stream>>>(aggh, xh, W1l, W1r, b1, hbuf, N);
  k_lin2<<<768, 256, 0, stream>>>(hbuf, W2l, W2r, b2, zh, rbuf, N);
  k_gather2b<<<(N + 3) / 4, 256, 0, stream>>>((const uint4*)zh, rbuf, csr,
                                              row_start, rend, invd, out, N);
}

// Round 12
// 307.936 us; speedup vs baseline: 6.0565x; 1.0748x over previous
//
#include <hip/hip_runtime.h>
#include <math.h>

#define IN_C 64
#define HID_C 128
#define OUT_C 64
#define NBK 256   // buckets of 512 nodes: bucket = dst >> 9
#define BD 64     // msplit bin ring depth
#define GS 16     // global atomic counter stride (ints) -> one 64B line each
// packed edge = (src<<9)|(dst&511); sentinel -1 unreachable (src <= N < 2^17).
// CSR rows padded to 8-multiples with dummy src = N (row N of xh/zh zeroed).

typedef __attribute__((ext_vector_type(8))) short bf16x8;   // 8 bf16 (4 VGPRs)
typedef __attribute__((ext_vector_type(4))) float f32x4;    // mfma C/D

__device__ __forceinline__ unsigned short f2bf(float f) {
  unsigned u = __float_as_uint(f);
  u = (u + 0x7FFFu + ((u >> 16) & 1u)) >> 16;  // RNE
  return (unsigned short)u;
}
__device__ __forceinline__ float bf2f(unsigned v) {  // low 16 bits = bf16
  return __uint_as_float(v << 16);
}
__device__ __forceinline__ unsigned pack2(float a, float b) {
  return (unsigned)f2bf(a) | ((unsigned)f2bf(b) << 16);
}

// ======== x -> bf16 (rows 0..N-1) + zero dummy row N ========
__global__ __launch_bounds__(256) void k_xcast(const float4* __restrict__ x4,
                                               uint2* __restrict__ xh2,
                                               int Mreal, int Mtot) {
  for (int i = blockIdx.x * 256 + threadIdx.x; i < Mtot; i += gridDim.x * 256) {
    uint2 p = {0u, 0u};
    if (i < Mreal) {
      float4 v = x4[i];
      p.x = pack2(v.x, v.y);
      p.y = pack2(v.z, v.w);
    }
    xh2[i] = p;
  }
}

// ======== bhist: LDS-local 256-bin histogram; line-padded merge target ======
__global__ __launch_bounds__(256) void k_bhistL(const int* __restrict__ dst,
                                                int* __restrict__ bh, int E) {
  __shared__ int h[NBK];
  int t = threadIdx.x;
  h[t] = 0;
  __syncthreads();
  for (int e = blockIdx.x * 256 + t; e < E; e += gridDim.x * 256)
    atomicAdd(&h[dst[e] >> 9], 1);
  __syncthreads();
  if (h[t]) atomicAdd(&bh[t * GS], h[t]);
}

// ======== scan: ebuf chunked-region starts + padded csr starts ========
// ebuf region: 16*min(cnt, cnt/16+512) (512 writer blocks, <=1 residual each).
// csr region: cnt + 4096 (pad <= 8 per node * 512 nodes/bucket).
__global__ __launch_bounds__(256) void k_bscan(const int* __restrict__ bh,
                                               int* __restrict__ bstart,
                                               int* __restrict__ rstart,
                                               int* __restrict__ gcur) {
  __shared__ int s1[NBK], s2[NBK];
  int t = threadIdx.x;
  int cnt = bh[t * GS];
  int region = 16 * min(cnt, (cnt >> 4) + 512);
  int creg = cnt + 4096;
  s1[t] = region; s2[t] = creg;
  __syncthreads();
  for (int off = 1; off < NBK; off <<= 1) {
    int a1 = (t >= off) ? s1[t - off] : 0;
    int a2 = (t >= off) ? s2[t - off] : 0;
    __syncthreads();
    s1[t] += a1; s2[t] += a2;
    __syncthreads();
  }
  int ex1 = s1[t] - region;
  int ex2 = s2[t] - creg;
  bstart[t] = ex1; gcur[t * GS] = ex1; rstart[t] = ex2;
}

// ======== multisplit: transposed ring bins, line-padded cursors ========
// bins[slot][bucket]: bank = bucket%32. gcur[b*GS]: one line per bucket ->
// chunk-alloc atomics pipeline across 256 lines instead of serializing on 16.
__global__ __launch_bounds__(256) void k_msplit(const int* __restrict__ src,
                                                const int* __restrict__ dst,
                                                int* __restrict__ gcur,
                                                int* __restrict__ ebuf, int E) {
  __shared__ int bcnt[NBK], bhead[NBK];
  __shared__ int bins[BD][NBK];
  int t = threadIdx.x;
  bcnt[t] = 0; bhead[t] = 0;
  int per = (E + gridDim.x - 1) / gridDim.x;
  int e0 = blockIdx.x * per, e1 = min(E, e0 + per);
  int e = e0 + t;
  int pb[4], pv[4]; int pc = 0;
  __syncthreads();
  for (;;) {
    // fetch up to 4 edges, then try to place pending
    while (pc < 4 && e < e1) {
      int d = dst[e], s = src[e];
      pb[pc] = d >> 9; pv[pc] = (s << 9) | (d & 511);
      pc++; e += 256;
    }
    for (int q = pc - 1; q >= 0; --q) {
      int pos = atomicAdd(&bcnt[pb[q]], 1);
      if (pos < BD) {
        bins[(bhead[pb[q]] + pos) & (BD - 1)][pb[q]] = pv[q];
        pc--;
        if (q != pc) { pb[q] = pb[pc]; pv[q] = pv[pc]; }
      }
    }
    int pending = __syncthreads_count(pc > 0 || e < e1);
    // flush: thread t owns bucket t
    int cntv = min(bcnt[t], BD);
    int head = bhead[t];
    while (cntv >= 16) {
      int base = atomicAdd(&gcur[t * GS], 16);
      int4 o[4];
#pragma unroll
      for (int k = 0; k < 16; ++k)
        ((int*)o)[k] = bins[(head + k) & (BD - 1)][t];
      int4* g = (int4*)(ebuf + base);
      g[0] = o[0]; g[1] = o[1]; g[2] = o[2]; g[3] = o[3];
      head = (head + 16) & (BD - 1);
      cntv -= 16;
    }
    bhead[t] = head;
    bcnt[t] = cntv;
    __syncthreads();
    if (!pending) break;
  }
  // residual: one sentinel-padded chunk per non-empty bucket
  int cntv = bcnt[t];
  if (cntv > 0) {
    int head = bhead[t];
    int base = atomicAdd(&gcur[t * GS], 16);
#pragma unroll
    for (int k = 0; k < 16; ++k)
      ebuf[base + k] = (k < cntv) ? bins[(head + k) & (BD - 1)][t] : -1;
  }
}

// ======== per-bucket local CSR (512 nodes/bucket), 8-padded rows ========
__global__ __launch_bounds__(512) void k_localcsr(const int* __restrict__ ebuf,
                                                  const int* __restrict__ bstart,
                                                  const int* __restrict__ gcur,
                                                  const int* __restrict__ rstart,
                                                  int* __restrict__ csr,
                                                  int* __restrict__ row_start,
                                                  int* __restrict__ rend,
                                                  float* __restrict__ invd, int N) {
  __shared__ int lcnt[512], loff[512], lcur[512];
  int t = threadIdx.x, b = blockIdx.x;
  int start = bstart[b], endp = gcur[b * GS], rs = rstart[b];
  lcnt[t] = 0;
  __syncthreads();
  for (int i = start + t; i < endp; i += 512) {
    int pe = ebuf[i];
    if (pe != -1) atomicAdd(&lcnt[pe & 511], 1);
  }
  __syncthreads();
  int v = lcnt[t];
  int pvn = (v + 7) & ~7;  // padded row length
  loff[t] = pvn;
  __syncthreads();
  for (int off = 1; off < 512; off <<= 1) {
    int a = (t >= off) ? loff[t - off] : 0;
    __syncthreads();
    loff[t] += a;
    __syncthreads();
  }
  int ex = loff[t] - pvn;
  lcur[t] = ex;
  int node = (b << 9) + t;
  if (node < N) {
    row_start[node] = rs + ex;
    rend[node] = rs + ex + pvn;
    invd[node] = 1.0f / fmaxf((float)v, 1.0f);
  }
  __syncthreads();
  for (int i = start + t; i < endp; i += 512) {
    int pe = ebuf[i];
    if (pe != -1) {
      int pos = atomicAdd(&lcur[pe & 511], 1);
      csr[rs + pos] = pe >> 9;
    }
  }
  for (int k = ex + v; k < ex + pvn; ++k) csr[rs + k] = N;
}

// ======== gather 1: branch-free, 8-lane x uint4 rows, bf16 in/out ========
__global__ __launch_bounds__(256) void k_gather1(const uint4* __restrict__ xh4,
                                                 const int* __restrict__ csr,
                                                 const int* __restrict__ row_start,
                                                 const int* __restrict__ rend,
                                                 const float* __restrict__ invd,
                                                 uint4* __restrict__ aggh4, int N) {
  int wid = (blockIdx.x * blockDim.x + threadIdx.x) >> 6;
  int lane = threadIdx.x & 63;
  if (wid >= N) return;
  int rq = lane >> 3, cq = lane & 7;
  int j = row_start[wid], end = rend[wid];
  float a0 = 0, a1 = 0, a2 = 0, a3 = 0, a4 = 0, a5 = 0, a6 = 0, a7 = 0;
#pragma unroll 2
  for (; j < end; j += 8) {
    int s = csr[j + rq];
    uint4 v = xh4[s * 8 + cq];
    a0 += bf2f(v.x & 0xffffu); a1 += bf2f(v.x >> 16);
    a2 += bf2f(v.y & 0xffffu); a3 += bf2f(v.y >> 16);
    a4 += bf2f(v.z & 0xffffu); a5 += bf2f(v.z >> 16);
    a6 += bf2f(v.w & 0xffffu); a7 += bf2f(v.w >> 16);
  }
#define RED8(d)                                               \
  a0 += __shfl_xor(a0, d); a1 += __shfl_xor(a1, d);           \
  a2 += __shfl_xor(a2, d); a3 += __shfl_xor(a3, d);           \
  a4 += __shfl_xor(a4, d); a5 += __shfl_xor(a5, d);           \
  a6 += __shfl_xor(a6, d); a7 += __shfl_xor(a7, d);
  RED8(8) RED8(16) RED8(32)
  if (rq == 0) {
    float inv = invd[wid];
    uint4 p;
    p.x = pack2(a0 * inv, a1 * inv);
    p.y = pack2(a2 * inv, a3 * inv);
    p.z = pack2(a4 * inv, a5 * inv);
    p.w = pack2(a6 * inv, a7 * inv);
    aggh4[wid * 8 + cq] = p;
  }
}

// ======== MFMA bf16 GEMM, layer 1: h(bf16) = relu([agg|x]@[W1l|W1r]^T + b1) ===
__global__ __launch_bounds__(256, 3) void k_lin1(
    const unsigned short* __restrict__ aggh, const unsigned short* __restrict__ xh,
    const float* __restrict__ W1l, const float* __restrict__ W1r,
    const float* __restrict__ b1, unsigned short* __restrict__ h, int N) {
  __shared__ __align__(16) unsigned short sW[128 * 136];
  __shared__ __align__(16) unsigned short sA[64 * 136];
  __shared__ float sb[128];
  int t = threadIdx.x;
  for (int i = t; i < 128 * 128; i += 256) {
    int o = i >> 7, k = i & 127;
    float w = (k < 64) ? W1l[o * 64 + k] : W1r[o * 64 + (k - 64)];
    sW[o * 136 + k] = f2bf(w);
  }
  if (t < 128) sb[t] = b1[t];
  int lane = t & 63, qm = lane >> 4, ln = lane & 15;
  int m0 = (t >> 6) * 16;
  __syncthreads();

  int ntiles = (N + 63) >> 6;
  for (int tile = blockIdx.x; tile < ntiles; tile += gridDim.x) {
    int base = tile << 6;
    for (int u = t; u < 64 * 64; u += 256) {
      int n = u >> 6, uu = u & 63;
      int node = base + n;
      unsigned v = 0;
      if (node < N) v = (uu < 32) ? ((const unsigned*)aggh)[node * 32 + uu]
                                  : ((const unsigned*)xh)[node * 32 + (uu - 32)];
      ((unsigned*)(sA + n * 136))[uu] = v;
    }
    __syncthreads();
    bf16x8 af[4];
#pragma unroll
    for (int kc = 0; kc < 4; ++kc)
      af[kc] = *(const bf16x8*)(sA + (m0 + ln) * 136 + kc * 32 + qm * 8);
#pragma unroll
    for (int ot = 0; ot < 8; ++ot) {
      int o0 = ot * 16;
      f32x4 acc = {0.f, 0.f, 0.f, 0.f};
#pragma unroll
      for (int kc = 0; kc < 4; ++kc) {
        bf16x8 bfr = *(const bf16x8*)(sW + (o0 + ln) * 136 + kc * 32 + qm * 8);
        acc = __builtin_amdgcn_mfma_f32_16x16x32_bf16(af[kc], bfr, acc, 0, 0, 0);
      }
      int col = o0 + ln;
      float bias = sb[col];
#pragma unroll
      for (int i = 0; i < 4; ++i) {
        int node = base + m0 + qm * 4 + i;
        if (node < N) h[node * 128 + col] = f2bf(fmaxf(acc[i] + bias, 0.f));
      }
    }
    __syncthreads();
  }
}

// ======== MFMA bf16 GEMM, layer 2: z(bf16)=h@W2l^T, r(fp32)=h@W2r^T + b2 ====
__global__ __launch_bounds__(256, 3) void k_lin2(
    const unsigned short* __restrict__ h, const float* __restrict__ W2l,
    const float* __restrict__ W2r, const float* __restrict__ b2,
    unsigned short* __restrict__ zh, float* __restrict__ r, int N) {
  __shared__ __align__(16) unsigned short sW[128 * 136];
  __shared__ __align__(16) unsigned short sA[64 * 136];
  __shared__ float sb2[64];
  int t = threadIdx.x;
  if (blockIdx.x == 0 && t < 32) ((unsigned*)zh)[N * 32 + t] = 0;
  for (int i = t; i < 128 * 128; i += 256) {
    int u = i >> 7, k = i & 127;
    float w = (u < 64) ? W2l[u * 128 + k] : W2r[(u - 64) * 128 + k];
    sW[u * 136 + k] = f2bf(w);
  }
  if (t < 64) sb2[t] = b2[t];
  int lane = t & 63, qm = lane >> 4, ln = lane & 15;
  int m0 = (t >> 6) * 16;
  __syncthreads();

  int ntiles = (N + 63) >> 6;
  for (int tile = blockIdx.x; tile < ntiles; tile += gridDim.x) {
    int base = tile << 6;
    for (int u = t; u < 64 * 64; u += 256) {
      int n = u >> 6, uu = u & 63;
      int node = base + n;
      unsigned v = 0;
      if (node < N) v = ((const unsigned*)h)[node * 64 + uu];
      ((unsigned*)(sA + n * 136))[uu] = v;
    }
    __syncthreads();
    bf16x8 af[4];
#pragma unroll
    for (int kc = 0; kc < 4; ++kc)
      af[kc] = *(const bf16x8*)(sA + (m0 + ln) * 136 + kc * 32 + qm * 8);
#pragma unroll
    for (int ot = 0; ot < 8; ++ot) {
      int o0 = ot * 16;
      f32x4 acc = {0.f, 0.f, 0.f, 0.f};
#pragma unroll
      for (int kc = 0; kc < 4; ++kc) {
        bf16x8 bfr = *(const bf16x8*)(sW + (o0 + ln) * 136 + kc * 32 + qm * 8);
        acc = __builtin_amdgcn_mfma_f32_16x16x32_bf16(af[kc], bfr, acc, 0, 0, 0);
      }
      int u = o0 + ln;  // u<64: z channel; u>=64: r channel u-64 (bias folded)
#pragma unroll
      for (int i = 0; i < 4; ++i) {
        int node = base + m0 + qm * 4 + i;
        if (node < N) {
          if (u < 64) zh[node * 64 + u] = f2bf(acc[i]);
          else        r[node * 64 + (u - 64)] = acc[i] + sb2[u - 64];
        }
      }
    }
    __syncthreads();
  }
}

// ======== gather 2 + epilogue: branch-free, 8-lane rows, sigmoid fused ======
__global__ __launch_bounds__(256) void k_gather2b(const uint4* __restrict__ zh4,
                                                  const float* __restrict__ r,
                                                  const int* __restrict__ csr,
                                                  const int* __restrict__ row_start,
                                                  const int* __restrict__ rend,
                                                  const float* __restrict__ invd,
                                                  float* __restrict__ out, int N) {
  int wid = (blockIdx.x * blockDim.x + threadIdx.x) >> 6;
  int lane = threadIdx.x & 63;
  if (wid >= N) return;
  int rq = lane >> 3, cq = lane & 7;
  int j = row_start[wid], end = rend[wid];
  float a0 = 0, a1 = 0, a2 = 0, a3 = 0, a4 = 0, a5 = 0, a6 = 0, a7 = 0;
#pragma unroll 2
  for (; j < end; j += 8) {
    int s = csr[j + rq];
    uint4 v = zh4[s * 8 + cq];
    a0 += bf2f(v.x & 0xffffu); a1 += bf2f(v.x >> 16);
    a2 += bf2f(v.y & 0xffffu); a3 += bf2f(v.y >> 16);
    a4 += bf2f(v.z & 0xffffu); a5 += bf2f(v.z >> 16);
    a6 += bf2f(v.w & 0xffffu); a7 += bf2f(v.w >> 16);
  }
  RED8(8) RED8(16) RED8(32)
  if (rq == 0) {
    float inv = invd[wid];
    const float4* r4 = (const float4*)r;
    float4 rv0 = r4[wid * 16 + cq * 2];
    float4 rv1 = r4[wid * 16 + cq * 2 + 1];
    float4 o0, o1;
    o0.x = 1.0f / (1.0f + __expf(-(a0 * inv + rv0.x)));
    o0.y = 1.0f / (1.0f + __expf(-(a1 * inv + rv0.y)));
    o0.z = 1.0f / (1.0f + __expf(-(a2 * inv + rv0.z)));
    o0.w = 1.0f / (1.0f + __expf(-(a3 * inv + rv0.w)));
    o1.x = 1.0f / (1.0f + __expf(-(a4 * inv + rv1.x)));
    o1.y = 1.0f / (1.0f + __expf(-(a5 * inv + rv1.y)));
    o1.z = 1.0f / (1.0f + __expf(-(a6 * inv + rv1.z)));
    o1.w = 1.0f / (1.0f + __expf(-(a7 * inv + rv1.w)));
    float4* out4 = (float4*)out;
    out4[wid * 16 + cq * 2] = o0;
    out4[wid * 16 + cq * 2 + 1] = o1;
  }
}

extern "C" void kernel_launch(void* const* d_in, const int* in_sizes, int n_in,
                              void* d_out, int out_size, void* d_ws, size_t ws_size,
                              hipStream_t stream) {
  const float* x   = (const float*)d_in[0];
  const int*   ei  = (const int*)d_in[1];
  const float* W1l = (const float*)d_in[2];
  const float* W1r = (const float*)d_in[3];
  const float* b1  = (const float*)d_in[4];
  const float* W2l = (const float*)d_in[5];
  const float* W2r = (const float*)d_in[6];
  const float* b2  = (const float*)d_in[7];
  float* out = (float*)d_out;

  int N = in_sizes[0] / IN_C;
  int E = in_sizes[1] / 2;
  const int* src = ei;
  const int* dst = ei + E;

  // ws: [bh 256*GS][gcur 256*GS][bstart 256][rstart 256][csr E+256*4096]
  //     [row_start N][rend N][invd N]
  //     [xh (N+1)*64 bf16][aggh N*64 bf16][zh (N+1)*64 bf16]  (ebuf aliases aggh+zh)
  //     [r N*64 f][h N*128 bf16]
  char* ws = (char*)d_ws;
  size_t off = 0;
  auto alignup = [](size_t v) { return (v + 511) & ~(size_t)511; };
  int* bh = (int*)(ws + off);         off = alignup(off + NBK * GS * 4);
  int* gcur = (int*)(ws + off);       off = alignup(off + NBK * GS * 4);
  int* bstart = (int*)(ws + off);     off = alignup(off + NBK * 4);
  int* rstart = (int*)(ws + off);     off = alignup(off + NBK * 4);
  int* csr = (int*)(ws + off);        off = alignup(off + ((size_t)E + NBK * 4096) * 4);
  int* row_start = (int*)(ws + off);  off = alignup(off + (size_t)N * 4);
  int* rend = (int*)(ws + off);       off = alignup(off + (size_t)N * 4);
  float* invd = (float*)(ws + off);   off = alignup(off + (size_t)N * 4);
  unsigned short* xh = (unsigned short*)(ws + off);   off = alignup(off + (size_t)(N + 1) * 64 * 2);
  unsigned short* aggh = (unsigned short*)(ws + off); off = alignup(off + (size_t)N * 64 * 2);
  unsigned short* zh = (unsigned short*)(ws + off);   off = alignup(off + (size_t)(N + 1) * 64 * 2);
  float* rbuf = (float*)(ws + off);   off = alignup(off + (size_t)N * 64 * 4);
  unsigned short* hbuf = (unsigned short*)(ws + off);
  int* ebuf = (int*)aggh;  // spans aggh+zh (~25.6MB >= 14.8MB worst-case chunked
                           // region); dead before k_gather1 / k_lin2 write them

  hipMemsetAsync(bh, 0, NBK * GS * 4, stream);
  k_xcast<<<2048, 256, 0, stream>>>((const float4*)x, (uint2*)xh, N * 16, (N + 1) * 16);
  k_bhistL<<<1024, 256, 0, stream>>>(dst, bh, E);
  k_bscan<<<1, NBK, 0, stream>>>(bh, bstart, rstart, gcur);
  k_msplit<<<512, 256, 0, stream>>>(src, dst, gcur, ebuf, E);
  k_localcsr<<<NBK, 512, 0, stream>>>(ebuf, bstart, gcur, rstart, csr,
                                      row_start, rend, invd, N);

  k_gather1<<<(N + 3) / 4, 256, 0, stream>>>((const uint4*)xh, csr, row_start,
                                             rend, invd, (uint4*)aggh, N);
  k_lin1<<<768, 256, 0, stream>>>(aggh, xh, W1l, W1r, b1, hbuf, N);
  k_lin2<<<768, 256, 0, stream>>>(hbuf, W2l, W2r, b2, zh, rbuf, N);
  k_gather2b<<<(N + 3) / 4, 256, 0, stream>>>((const uint4*)zh, rbuf, csr,
                                              row_start, rend, invd, out, N);
}